// Round 8
// baseline (389.913 us; speedup 1.0000x reference)
//
#include <hip/hip_runtime.h>
#include <hip/hip_bf16.h>

typedef unsigned short ushort_t;
typedef __bf16 bf16x8 __attribute__((ext_vector_type(8)));
typedef float f32x4 __attribute__((ext_vector_type(4)));
typedef float f32x8 __attribute__((ext_vector_type(8)));

#define NTOK 1032
#define NROWS 8256       // B*N = 8*1032
#define DIMC 1024
#define QKV_ELEMS 8454144  // 8*16*1032*64 elements per tensor
#define XE 8454144         // X elements (8256*1024)
#define QWE 3145728        // qkv_w elements (3072*1024)
#define OWE 1048576        // out_w elements (1024*1024)

__device__ __forceinline__ float bf2f(ushort_t u) {
    union { unsigned int i; float f; } v; v.i = ((unsigned int)u) << 16; return v.f;
}
__device__ __forceinline__ ushort_t f2bf(float f) {
    union { float f; unsigned int i; } v; v.f = f;
    unsigned int r = v.i + 0x7fffu + ((v.i >> 16) & 1u);
    return (ushort_t)(r >> 16);
}
__device__ __forceinline__ bf16x8 cvt8(const float* p) {
    const float4 a = *(const float4*)p;
    const float4 b = *(const float4*)(p + 4);
    bf16x8 r;
    r[0] = (__bf16)a.x; r[1] = (__bf16)a.y; r[2] = (__bf16)a.z; r[3] = (__bf16)a.w;
    r[4] = (__bf16)b.x; r[5] = (__bf16)b.y; r[6] = (__bf16)b.z; r[7] = (__bf16)b.w;
    return r;
}
__device__ __forceinline__ void load_lds16(const ushort_t* g, ushort_t* l) {
    __builtin_amdgcn_global_load_lds(
        (const __attribute__((address_space(1))) unsigned int*)g,
        (__attribute__((address_space(3))) unsigned int*)l, 16, 0, 0);
}

// ---------------------------------------------------------------------------
// fp32 -> bf16 pre-conversion of X, qkv_w, out_w (RNE).
// ---------------------------------------------------------------------------
__global__ __launch_bounds__(256) void cvt_kernel(
    const float* __restrict__ X, const float* __restrict__ Wq,
    const float* __restrict__ Wo,
    ushort_t* __restrict__ Xb, ushort_t* __restrict__ Wqb,
    ushort_t* __restrict__ Wob)
{
    const long i8 = ((long)blockIdx.x * 256 + threadIdx.x) * 8;
    const float* src;
    ushort_t* dst;
    long off;
    if (i8 < XE)            { src = X;  dst = Xb;  off = i8; }
    else if (i8 < XE + QWE) { src = Wq; dst = Wqb; off = i8 - XE; }
    else                    { src = Wo; dst = Wob; off = i8 - XE - QWE; }
    *(bf16x8*)(dst + off) = cvt8(src + off);
}

// ---------------------------------------------------------------------------
// GEMM, m97 K-loop. MODE 0 epilogue FUSES RMSNorm+RoPE for Q/K parts via an
// LDS tile re-pass (one thread per head-token), and transposes V through LDS
// into dim-major Vt with contiguous 16B stores. MODE 1: plain fp32 store.
// ---------------------------------------------------------------------------
template<int MODE>
__global__ __launch_bounds__(256) void gemm_kernel(
    const ushort_t* __restrict__ A, const ushort_t* __restrict__ W,
    ushort_t* __restrict__ QKV, float* __restrict__ Out,
    const float* __restrict__ cosb, const float* __restrict__ sinb,
    const float* __restrict__ nqw, const float* __restrict__ nkw)
{
    __shared__ __align__(16) ushort_t SM[17408];   // 34816 B: As|Bs in K-loop, T in epilogue
    __shared__ float wsh[64];
    ushort_t* As = SM;            // [128*32]
    ushort_t* Bs = SM + 4096;     // [128*32]

    const int tid  = threadIdx.x;
    const int wave = tid >> 6, lane = tid & 63;
    const int m0 = blockIdx.y * 128;
    const int n0 = blockIdx.x * 128;

    f32x4 acc[4][4] = {};

    const int s0 = tid, s1 = tid + 256;
    int ar0 = m0 + (s0 >> 2); if (ar0 > NROWS - 1) ar0 = NROWS - 1;
    int ar1 = m0 + (s1 >> 2); if (ar1 > NROWS - 1) ar1 = NROWS - 1;
    const int br0 = n0 + (s0 >> 2);
    const int br1 = n0 + (s1 >> 2);
    const int kc0 = (s0 & 3) * 8, kc1 = (s1 & 3) * 8;

    const ushort_t* ga0 = A + (long)ar0 * DIMC + kc0;
    const ushort_t* ga1 = A + (long)ar1 * DIMC + kc1;
    const ushort_t* gw0 = W + (long)br0 * DIMC + kc0;
    const ushort_t* gw1 = W + (long)br1 * DIMC + kc1;
    ushort_t* la0 = &As[s0 * 8];
    ushort_t* la1 = &As[s1 * 8];
    ushort_t* lb0 = &Bs[s0 * 8];
    ushort_t* lb1 = &Bs[s1 * 8];

    const int wm = (wave >> 1) * 64, wn = (wave & 1) * 64;
    const int fr = lane & 15, fk = (lane >> 4) * 8;

    for (int k0 = 0; k0 < DIMC; k0 += 32) {
        load_lds16(ga0 + k0, la0);
        load_lds16(ga1 + k0, la1);
        load_lds16(gw0 + k0, lb0);
        load_lds16(gw1 + k0, lb1);
        __syncthreads();

        bf16x8 af[4], bfr[4];
        #pragma unroll
        for (int mi = 0; mi < 4; ++mi)
            af[mi] = *(const bf16x8*)&As[(wm + mi * 16 + fr) * 32 + fk];
        #pragma unroll
        for (int ni = 0; ni < 4; ++ni)
            bfr[ni] = *(const bf16x8*)&Bs[(wn + ni * 16 + fr) * 32 + fk];
        #pragma unroll
        for (int mi = 0; mi < 4; ++mi)
            #pragma unroll
            for (int ni = 0; ni < 4; ++ni)
                acc[mi][ni] = __builtin_amdgcn_mfma_f32_16x16x32_bf16(
                    af[mi], bfr[ni], acc[mi][ni], 0, 0, 0);
        __syncthreads();
    }

    const int col = lane & 15, rb = (lane >> 4) * 4;

    if (MODE == 0) {
        const int part = n0 >> 10;
        if (part < 2) {
            // ---- Q/K: tile -> LDS [m 128][o 136], then fused RMSNorm+RoPE ----
            if (tid < 64) wsh[tid] = (part == 0 ? nqw : nkw)[tid];
            #pragma unroll
            for (int mi = 0; mi < 4; ++mi)
                #pragma unroll
                for (int ni = 0; ni < 4; ++ni) {
                    const int ol = wn + ni * 16 + col;
                    #pragma unroll
                    for (int reg = 0; reg < 4; ++reg)
                        SM[(wm + mi * 16 + rb + reg) * 136 + ol] = f2bf(acc[mi][ni][reg]);
                }
            __syncthreads();

            const int hl = tid >> 7, r = tid & 127;
            const int m = m0 + r;
            if (m < NROWS) {
                const int bb = m / NTOK, n = m - bb * NTOK;
                const int hg = ((n0 & 1023) >> 6) + hl;
                const int bh = bb * 16 + hg;
                const ushort_t* Trow = &SM[r * 136 + hl * 64];
                bf16x8 xc[8];
                #pragma unroll
                for (int c = 0; c < 8; ++c) xc[c] = *(const bf16x8*)(Trow + c * 8);
                float ss = 0.f;
                #pragma unroll
                for (int c = 0; c < 8; ++c) {
                    const f32x8 xf = __builtin_convertvector(xc[c], f32x8);
                    #pragma unroll
                    for (int e = 0; e < 8; ++e) ss += xf[e] * xf[e];
                }
                const float rms = rsqrtf(ss * (1.0f / 64.0f) + 1e-6f);
                const float* cosp = cosb + n * 64;
                const float* sinp = sinb + n * 64;
                ushort_t* dst = QKV + (long)part * QKV_ELEMS + ((long)bh * NTOK + n) * 64;
                #pragma unroll
                for (int c = 0; c < 8; ++c) {
                    const f32x8 xf = __builtin_convertvector(xc[c], f32x8);
                    const f32x8 pf = __builtin_convertvector(xc[c ^ 4], f32x8);
                    const float sgn = (c < 4) ? -1.f : 1.f;
                    bf16x8 o8;
                    #pragma unroll
                    for (int e = 0; e < 8; ++e) {
                        const float xn  = xf[e] * rms * wsh[c * 8 + e];
                        const float rot = sgn * pf[e] * rms * wsh[(c ^ 4) * 8 + e];
                        o8[e] = (__bf16)(xn * cosp[c * 8 + e] + rot * sinp[c * 8 + e]);
                    }
                    *(bf16x8*)(dst + c * 8) = o8;
                }
            }
        } else {
            // ---- V: transpose via LDS [o 128][m 136], contiguous Vt stores ----
            #pragma unroll
            for (int mi = 0; mi < 4; ++mi)
                #pragma unroll
                for (int ni = 0; ni < 4; ++ni) {
                    const int ol = wn + ni * 16 + col;
                    #pragma unroll
                    for (int reg = 0; reg < 4; ++reg)
                        SM[ol * 136 + wm + mi * 16 + rb + reg] = f2bf(acc[mi][ni][reg]);
                }
            __syncthreads();

            const int ol = tid >> 1, half = tid & 1;
            const int o = n0 + ol;
            const int hg = (o & 1023) >> 6, d = o & 63;
            #pragma unroll
            for (int c = 0; c < 8; ++c) {
                const int m = m0 + half * 64 + c * 8;   // 8-aligned run; 1032%8==0
                if (m < NROWS) {
                    const int bb = m / NTOK, n = m - bb * NTOK;
                    const long dst = 2L * QKV_ELEMS +
                        ((long)((bb * 16 + hg) * 64 + d)) * NTOK + n;
                    *(bf16x8*)(QKV + dst) =
                        *(const bf16x8*)&SM[ol * 136 + half * 64 + c * 8];
                }
            }
        }
    } else {
        #pragma unroll
        for (int mi = 0; mi < 4; ++mi)
            #pragma unroll
            for (int ni = 0; ni < 4; ++ni) {
                const int o = n0 + wn + ni * 16 + col;
                #pragma unroll
                for (int reg = 0; reg < 4; ++reg) {
                    const int m = m0 + wm + mi * 16 + rb + reg;
                    if (m < NROWS) Out[(long)m * DIMC + o] = acc[mi][ni][reg];
                }
            }
    }
}

// ---------------------------------------------------------------------------
// Patch attention (unchanged from round 7).
// ---------------------------------------------------------------------------
__global__ __launch_bounds__(256) void attn_patch_kernel(
    const ushort_t* __restrict__ Qb, const ushort_t* __restrict__ Kb,
    const ushort_t* __restrict__ Vt, ushort_t* __restrict__ AO)
{
    __shared__ __align__(16) ushort_t KP_s[256 * 72];
    __shared__ float l_s[32];

    const int tid = threadIdx.x;
    const int wave = tid >> 6, lane = tid & 63;
    const int m_ = lane & 15, quad = lane >> 4;
    const int bh = blockIdx.x >> 5, qr = blockIdx.x & 31;
    const int b = bh >> 4, h = bh & 15;

    int r0 = qr - 3; if (r0 < 0) r0 = 0;
    int r1 = qr + 3; if (r1 > 31) r1 = 31;
    const int nrows = r1 - r0 + 1;
    const int limit = 8 + nrows * 32;

    const ushort_t* Qg  = Qb + ((long)bh * NTOK + 8 + qr * 32) * 64;
    const ushort_t* Kg  = Kb + (long)bh * NTOK * 64;
    const ushort_t* Vtg = Vt + (long)bh * 64 * NTOK;

    if (tid < 32) l_s[tid] = 0.f;

    bf16x8 af[2][2];
    #pragma unroll
    for (int mt = 0; mt < 2; ++mt)
        #pragma unroll
        for (int ks = 0; ks < 2; ++ks)
            af[mt][ks] = *(const bf16x8*)(Qg + (mt * 16 + m_) * 64 + ks * 32 + quad * 8);

    for (int c = tid; c < limit * 8; c += 256) {
        const int slot = c >> 3, c8 = (c & 7) * 8;
        const int tok = slot + (slot >= 8 ? r0 * 32 : 0);
        *(bf16x8*)&KP_s[slot * 72 + c8] = *(const bf16x8*)(Kg + (long)tok * 64 + c8);
    }
    __syncthreads();

    const int nb = wave * 64;
    bf16x8 bfr[4][2];
    #pragma unroll
    for (int nt = 0; nt < 4; ++nt)
        #pragma unroll
        for (int ks = 0; ks < 2; ++ks)
            bfr[nt][ks] = *(const bf16x8*)&KP_s[(nb + nt * 16 + m_) * 72 + ks * 32 + quad * 8];

    f32x4 sacc[2][4] = {};
    #pragma unroll
    for (int mt = 0; mt < 2; ++mt)
        #pragma unroll
        for (int nt = 0; nt < 4; ++nt) {
            sacc[mt][nt] = __builtin_amdgcn_mfma_f32_16x16x32_bf16(
                af[mt][0], bfr[nt][0], sacc[mt][nt], 0, 0, 0);
            sacc[mt][nt] = __builtin_amdgcn_mfma_f32_16x16x32_bf16(
                af[mt][1], bfr[nt][1], sacc[mt][nt], 0, 0, 0);
        }
    __syncthreads();

    #pragma unroll
    for (int mt = 0; mt < 2; ++mt)
        #pragma unroll
        for (int nt = 0; nt < 4; ++nt) {
            const int slot = nb + nt * 16 + m_;
            const int kc = (slot - 8) & 31;
            #pragma unroll
            for (int reg = 0; reg < 4; ++reg) {
                const int qm = mt * 16 + quad * 4 + reg;
                const bool val = (slot < 8) ||
                    ((slot < limit) && ((unsigned)(kc - qm + 3) <= 6u));
                const float s = sacc[mt][nt][reg];
                const float p = val ? __expf(s * 0.125f) : 0.f;
                KP_s[qm * 280 + slot] = f2bf(p);
                float rs = p;
                #pragma unroll
                for (int off = 1; off < 16; off <<= 1) rs += __shfl_xor(rs, off);
                if (m_ == 0) atomicAdd(&l_s[qm], rs);
            }
        }
    __syncthreads();

    {
        const int d0 = wave * 16;
        f32x4 oacc[2] = {};
        #pragma unroll
        for (int ks = 0; ks < 8; ++ks) {
            const int slot0 = ks * 32 + quad * 8;
            int tok0;
            if (slot0 >= limit) tok0 = 0;
            else if (slot0 < 8) tok0 = slot0;
            else tok0 = 8 + r0 * 32 + (slot0 - 8);
            const bf16x8 bv = *(const bf16x8*)(Vtg + (long)(d0 + m_) * NTOK + tok0);
            #pragma unroll
            for (int mt = 0; mt < 2; ++mt) {
                const bf16x8 ap = *(const bf16x8*)&KP_s[(mt * 16 + m_) * 280 + ks * 32 + quad * 8];
                oacc[mt] = __builtin_amdgcn_mfma_f32_16x16x32_bf16(ap, bv, oacc[mt], 0, 0, 0);
            }
        }
        #pragma unroll
        for (int mt = 0; mt < 2; ++mt)
            #pragma unroll
            for (int reg = 0; reg < 4; ++reg) {
                const int qm = mt * 16 + quad * 4 + reg;
                const int tok = 8 + qr * 32 + qm;
                const float rl = l_s[qm];
                AO[((long)(b * NTOK + tok)) * DIMC + h * 64 + wave * 16 + m_] =
                    f2bf(oacc[mt][reg] / rl);
            }
    }
}

// ---------------------------------------------------------------------------
// Special-token attention (unchanged from round 7).
// ---------------------------------------------------------------------------
__global__ __launch_bounds__(256) void attn_special_kernel(
    const ushort_t* __restrict__ Qb, const ushort_t* __restrict__ Kb,
    const ushort_t* __restrict__ Vt, ushort_t* __restrict__ AO)
{
    __shared__ __align__(16) ushort_t Q_s[16 * 72];
    __shared__ __align__(16) ushort_t K_s[256 * 72];
    __shared__ __align__(16) ushort_t P_s[16 * 280];
    __shared__ float l_s[16];

    const int tid = threadIdx.x;
    const int wave = tid >> 6, lane = tid & 63;
    const int m_ = lane & 15, quad = lane >> 4;
    const int bh = blockIdx.x;
    const int b = bh >> 4, h = bh & 15;

    const ushort_t* Kg  = Kb + (long)bh * NTOK * 64;
    const ushort_t* Vtg = Vt + (long)bh * 64 * NTOK;

    if (tid < 16) l_s[tid] = 0.f;
    if (tid < 128) {
        const int row = tid >> 3, c8 = (tid & 7) * 8;
        bf16x8 v;
        if (row < 8) {
            v = *(const bf16x8*)(Qb + ((long)bh * NTOK + row) * 64 + c8);
        } else {
            #pragma unroll
            for (int e = 0; e < 8; ++e) v[e] = (__bf16)0.f;
        }
        *(bf16x8*)&Q_s[row * 72 + c8] = v;
    }

    const int d0 = wave * 16;
    const int nb = wave * 64;
    f32x4 oacc = {};

    for (int ch = 0; ch < 5; ++ch) {
        const int tok0 = ch * 256;
        const int limit = (NTOK - tok0 < 256) ? (NTOK - tok0) : 256;
        __syncthreads();
        for (int c = tid; c < limit * 8; c += 256) {
            const int slot = c >> 3, c8 = (c & 7) * 8;
            *(bf16x8*)&K_s[slot * 72 + c8] =
                *(const bf16x8*)(Kg + (long)(tok0 + slot) * 64 + c8);
        }
        __syncthreads();

        {
            bf16x8 af[2], bfr[4][2];
            #pragma unroll
            for (int ks = 0; ks < 2; ++ks)
                af[ks] = *(const bf16x8*)&Q_s[m_ * 72 + ks * 32 + quad * 8];
            #pragma unroll
            for (int nt = 0; nt < 4; ++nt)
                #pragma unroll
                for (int ks = 0; ks < 2; ++ks)
                    bfr[nt][ks] = *(const bf16x8*)&K_s[(nb + nt * 16 + m_) * 72 + ks * 32 + quad * 8];
            f32x4 sacc[4] = {};
            #pragma unroll
            for (int nt = 0; nt < 4; ++nt) {
                sacc[nt] = __builtin_amdgcn_mfma_f32_16x16x32_bf16(af[0], bfr[nt][0], sacc[nt], 0, 0, 0);
                sacc[nt] = __builtin_amdgcn_mfma_f32_16x16x32_bf16(af[1], bfr[nt][1], sacc[nt], 0, 0, 0);
            }
            #pragma unroll
            for (int nt = 0; nt < 4; ++nt) {
                const int slot = nb + nt * 16 + m_;
                const bool val = (slot < limit);
                #pragma unroll
                for (int reg = 0; reg < 4; ++reg) {
                    const int qm = quad * 4 + reg;
                    const float p = val ? __expf(sacc[nt][reg] * 0.125f) : 0.f;
                    P_s[qm * 280 + slot] = f2bf(p);
                    float rs = p;
                    #pragma unroll
                    for (int off = 1; off < 16; off <<= 1) rs += __shfl_xor(rs, off);
                    if (m_ == 0 && qm < 8) atomicAdd(&l_s[qm], rs);
                }
            }
        }
        __syncthreads();

        #pragma unroll
        for (int ks = 0; ks < 8; ++ks) {
            const int slot0 = ks * 32 + quad * 8;
            const int tok = tok0 + ((slot0 < limit) ? slot0 : 0);
            const bf16x8 bv = *(const bf16x8*)(Vtg + (long)(d0 + m_) * NTOK + tok);
            const bf16x8 ap = *(const bf16x8*)&P_s[m_ * 280 + ks * 32 + quad * 8];
            oacc = __builtin_amdgcn_mfma_f32_16x16x32_bf16(ap, bv, oacc, 0, 0, 0);
        }
    }
    __syncthreads();

    #pragma unroll
    for (int reg = 0; reg < 4; ++reg) {
        const int qm = quad * 4 + reg;
        if (qm < 8) {
            AO[((long)(b * NTOK + qm)) * DIMC + h * 64 + d0 + m_] =
                f2bf(oacc[reg] / l_s[qm]);
        }
    }
}

extern "C" void kernel_launch(void* const* d_in, const int* in_sizes, int n_in,
                              void* d_out, int out_size, void* d_ws, size_t ws_size,
                              hipStream_t stream) {
    const float* X    = (const float*)d_in[0];
    const float* fc   = (const float*)d_in[1];
    const float* fs   = (const float*)d_in[2];
    const float* qkvw = (const float*)d_in[3];
    const float* outw = (const float*)d_in[4];
    const float* nqw  = (const float*)d_in[5];
    const float* nkw  = (const float*)d_in[6];

    ushort_t* Qb  = (ushort_t*)d_ws;     // 16.9 MB each
    ushort_t* Kb  = Qb + QKV_ELEMS;
    ushort_t* Vt  = Kb + QKV_ELEMS;      // dim-major [bh][d][n]
    ushort_t* AO  = Vt + QKV_ELEMS;
    ushort_t* Xb  = AO + QKV_ELEMS;      // bf16 X (16.9 MB)
    ushort_t* Wqb = Xb + XE;             // bf16 qkv_w (6.3 MB)
    ushort_t* Wob = Wqb + QWE;           // bf16 out_w (2.1 MB)
    float* Out = (float*)d_out;

    cvt_kernel<<<6176, 256, 0, stream>>>(X, qkvw, outw, Xb, Wqb, Wob);
    // QKV projection with fused RMSNorm+RoPE epilogue (rope_kernel eliminated)
    gemm_kernel<0><<<dim3(24, 65), 256, 0, stream>>>(Xb, Wqb, Qb, nullptr, fc, fs, nqw, nkw);
    attn_patch_kernel<<<4096, 256, 0, stream>>>(Qb, Kb, Vt, AO);
    attn_special_kernel<<<128, 256, 0, stream>>>(Qb, Kb, Vt, AO);
    gemm_kernel<1><<<dim3(8, 65), 256, 0, stream>>>(AO, Wob, nullptr, Out, nullptr, nullptr, nullptr, nullptr);
}

// Round 9
// 365.952 us; speedup vs baseline: 1.0655x; 1.0655x over previous
//
#include <hip/hip_runtime.h>
#include <hip/hip_bf16.h>

typedef unsigned short ushort_t;
typedef __bf16 bf16x8 __attribute__((ext_vector_type(8)));
typedef float f32x4 __attribute__((ext_vector_type(4)));

#define NTOK 1032
#define NROWS 8256       // B*N = 8*1032
#define DIMC 1024
#define QKV_ELEMS 8454144  // 8*16*1032*64 elements per tensor
#define XE 8454144         // X elements (8256*1024)
#define QWE 3145728        // qkv_w elements (3072*1024)
#define OWE 1048576        // out_w elements (1024*1024)

__device__ __forceinline__ float bf2f(ushort_t u) {
    union { unsigned int i; float f; } v; v.i = ((unsigned int)u) << 16; return v.f;
}
__device__ __forceinline__ ushort_t f2bf(float f) {
    union { float f; unsigned int i; } v; v.f = f;
    unsigned int r = v.i + 0x7fffu + ((v.i >> 16) & 1u);
    return (ushort_t)(r >> 16);
}
__device__ __forceinline__ bf16x8 cvt8(const float* p) {
    const float4 a = *(const float4*)p;
    const float4 b = *(const float4*)(p + 4);
    bf16x8 r;
    r[0] = (__bf16)a.x; r[1] = (__bf16)a.y; r[2] = (__bf16)a.z; r[3] = (__bf16)a.w;
    r[4] = (__bf16)b.x; r[5] = (__bf16)b.y; r[6] = (__bf16)b.z; r[7] = (__bf16)b.w;
    return r;
}
__device__ __forceinline__ void load_lds16(const ushort_t* g, ushort_t* l) {
    __builtin_amdgcn_global_load_lds(
        (const __attribute__((address_space(1))) unsigned int*)g,
        (__attribute__((address_space(3))) unsigned int*)l, 16, 0, 0);
}

// ---------------------------------------------------------------------------
// fp32 -> bf16 pre-conversion of X, qkv_w, out_w (RNE).
// ---------------------------------------------------------------------------
__global__ __launch_bounds__(256) void cvt_kernel(
    const float* __restrict__ X, const float* __restrict__ Wq,
    const float* __restrict__ Wo,
    ushort_t* __restrict__ Xb, ushort_t* __restrict__ Wqb,
    ushort_t* __restrict__ Wob)
{
    const long i8 = ((long)blockIdx.x * 256 + threadIdx.x) * 8;
    const float* src;
    ushort_t* dst;
    long off;
    if (i8 < XE)            { src = X;  dst = Xb;  off = i8; }
    else if (i8 < XE + QWE) { src = Wq; dst = Wqb; off = i8 - XE; }
    else                    { src = Wo; dst = Wob; off = i8 - XE - QWE; }
    *(bf16x8*)(dst + off) = cvt8(src + off);
}

// ---------------------------------------------------------------------------
// GEMM, m97 K-loop (72-VGPR class, LDS 16 KB). SWAP selects mfma(B,A) so the
// 4 accumulator regs are contiguous along the dim we want to store along:
//   MODE 0, SWAP=1 (Q/K parts): regs contiguous in d  -> 8B bf16x4 stores
//   MODE 0, SWAP=0 (V part):    regs contiguous in n  -> 8B stores to dim-major Vt
//   MODE 1, SWAP=1 (out proj):  regs contiguous in o  -> 16B float4 stores
// Operand swap is value-exact (same MACs, same order); fragment load pattern
// is identical for A and B operands of mfma_16x16x32.
// ---------------------------------------------------------------------------
template<int MODE, bool SWAP>
__global__ __launch_bounds__(256) void gemm_kernel(
    const ushort_t* __restrict__ A, const ushort_t* __restrict__ W,
    ushort_t* __restrict__ QKV, float* __restrict__ Out, int n_base)
{
    __shared__ __align__(16) ushort_t As[128 * 32];
    __shared__ __align__(16) ushort_t Bs[128 * 32];
    const int tid  = threadIdx.x;
    const int wave = tid >> 6, lane = tid & 63;
    const int m0 = blockIdx.y * 128;
    const int n0 = n_base + blockIdx.x * 128;

    f32x4 acc[4][4] = {};

    const int s0 = tid, s1 = tid + 256;
    int ar0 = m0 + (s0 >> 2); if (ar0 > NROWS - 1) ar0 = NROWS - 1;
    int ar1 = m0 + (s1 >> 2); if (ar1 > NROWS - 1) ar1 = NROWS - 1;
    const int br0 = n0 + (s0 >> 2);
    const int br1 = n0 + (s1 >> 2);
    const int kc0 = (s0 & 3) * 8, kc1 = (s1 & 3) * 8;

    const ushort_t* ga0 = A + (long)ar0 * DIMC + kc0;
    const ushort_t* ga1 = A + (long)ar1 * DIMC + kc1;
    const ushort_t* gw0 = W + (long)br0 * DIMC + kc0;
    const ushort_t* gw1 = W + (long)br1 * DIMC + kc1;
    ushort_t* la0 = &As[s0 * 8];
    ushort_t* la1 = &As[s1 * 8];
    ushort_t* lb0 = &Bs[s0 * 8];
    ushort_t* lb1 = &Bs[s1 * 8];

    const int wm = (wave >> 1) * 64, wn = (wave & 1) * 64;
    const int fr = lane & 15, fk = (lane >> 4) * 8;

    for (int k0 = 0; k0 < DIMC; k0 += 32) {
        load_lds16(ga0 + k0, la0);
        load_lds16(ga1 + k0, la1);
        load_lds16(gw0 + k0, lb0);
        load_lds16(gw1 + k0, lb1);
        __syncthreads();

        bf16x8 af[4], bfr[4];
        #pragma unroll
        for (int mi = 0; mi < 4; ++mi)
            af[mi] = *(const bf16x8*)&As[(wm + mi * 16 + fr) * 32 + fk];
        #pragma unroll
        for (int ni = 0; ni < 4; ++ni)
            bfr[ni] = *(const bf16x8*)&Bs[(wn + ni * 16 + fr) * 32 + fk];
        #pragma unroll
        for (int mi = 0; mi < 4; ++mi)
            #pragma unroll
            for (int ni = 0; ni < 4; ++ni) {
                if (SWAP)
                    acc[mi][ni] = __builtin_amdgcn_mfma_f32_16x16x32_bf16(
                        bfr[ni], af[mi], acc[mi][ni], 0, 0, 0);
                else
                    acc[mi][ni] = __builtin_amdgcn_mfma_f32_16x16x32_bf16(
                        af[mi], bfr[ni], acc[mi][ni], 0, 0, 0);
            }
        __syncthreads();
    }

    const int col = lane & 15, rb = (lane >> 4) * 4;

    if (MODE == 0 && SWAP) {
        // Q/K parts: D[o][m] layout -> col=m, regs contiguous in o (=d)
        const int part = n0 >> 10;
        #pragma unroll
        for (int mi = 0; mi < 4; ++mi) {
            const int m = m0 + wm + mi * 16 + col;
            if (m < NROWS) {
                const int bb = m / NTOK, n = m - bb * NTOK;
                #pragma unroll
                for (int ni = 0; ni < 4; ++ni) {
                    const int rem = (n0 & 1023) + wn + ni * 16 + rb;
                    const int hg = rem >> 6, d = rem & 63;
                    ushort4 pk;
                    pk.x = f2bf(acc[mi][ni][0]);
                    pk.y = f2bf(acc[mi][ni][1]);
                    pk.z = f2bf(acc[mi][ni][2]);
                    pk.w = f2bf(acc[mi][ni][3]);
                    *(ushort4*)(QKV + (long)part * QKV_ELEMS +
                        ((long)(bb * 16 + hg) * NTOK + n) * 64 + d) = pk;
                }
            }
        }
    } else if (MODE == 0) {
        // V part: D[m][o] layout -> regs contiguous in m (=n), store to Vt[bh][d][n]
        #pragma unroll
        for (int ni = 0; ni < 4; ++ni) {
            const int o = n0 + wn + ni * 16 + col;
            const int rem = o & 1023;
            const int hg = rem >> 6, d = rem & 63;
            #pragma unroll
            for (int mi = 0; mi < 4; ++mi) {
                const int mb = m0 + wm + mi * 16 + rb;   // 4-aligned run of 4
                if (mb < NROWS) {
                    const int bb = mb / NTOK, n = mb - bb * NTOK;
                    ushort4 pk;
                    pk.x = f2bf(acc[mi][ni][0]);
                    pk.y = f2bf(acc[mi][ni][1]);
                    pk.z = f2bf(acc[mi][ni][2]);
                    pk.w = f2bf(acc[mi][ni][3]);
                    *(ushort4*)(QKV + 2L * QKV_ELEMS +
                        ((long)((bb * 16 + hg) * 64 + d)) * NTOK + n) = pk;
                }
            }
        }
    } else {
        // out proj (SWAP): col=m, regs contiguous in o -> float4 stores
        #pragma unroll
        for (int mi = 0; mi < 4; ++mi) {
            const int m = m0 + wm + mi * 16 + col;
            if (m < NROWS) {
                #pragma unroll
                for (int ni = 0; ni < 4; ++ni) {
                    const int o = n0 + wn + ni * 16 + rb;
                    float4 pk;
                    pk.x = acc[mi][ni][0];
                    pk.y = acc[mi][ni][1];
                    pk.z = acc[mi][ni][2];
                    pk.w = acc[mi][ni][3];
                    *(float4*)(Out + (long)m * DIMC + o) = pk;
                }
            }
        }
    }
}

// ---------------------------------------------------------------------------
// RMSNorm + RoPE in-place on bf16 Q / K (token-major). Round-7 version.
// ---------------------------------------------------------------------------
__global__ __launch_bounds__(256) void rope_kernel(
    ushort_t* __restrict__ Qb, ushort_t* __restrict__ Kb,
    const float* __restrict__ cosb, const float* __restrict__ sinb,
    const float* __restrict__ wq, const float* __restrict__ wk)
{
    const int wave = threadIdx.x >> 6, lane = threadIdx.x & 63;
    const int t = blockIdx.x * 4 + wave;
    const int tensor = (t >= 132096) ? 1 : 0;
    const int r = t - tensor * 132096;
    const int n = r % NTOK;
    ushort_t* base = (tensor ? Kb : Qb) + (long)r * 64;

    const float x = bf2f(base[lane]);
    float ss = x * x;
    #pragma unroll
    for (int off = 32; off; off >>= 1) ss += __shfl_xor(ss, off);
    const float rms = rsqrtf(ss * (1.0f / 64.0f) + 1e-6f);
    const float w = (tensor ? wk : wq)[lane];
    const float xn = x * rms * w;
    const float partner = __shfl_xor(xn, 32);
    const float rot = (lane < 32) ? -partner : partner;
    const float c = cosb[n * 64 + lane];
    const float s = sinb[n * 64 + lane];
    base[lane] = f2bf(xn * c + rot * s);
}

// ---------------------------------------------------------------------------
// Patch attention (unchanged from round 7).
// ---------------------------------------------------------------------------
__global__ __launch_bounds__(256) void attn_patch_kernel(
    const ushort_t* __restrict__ Qb, const ushort_t* __restrict__ Kb,
    const ushort_t* __restrict__ Vt, ushort_t* __restrict__ AO)
{
    __shared__ __align__(16) ushort_t KP_s[256 * 72];
    __shared__ float l_s[32];

    const int tid = threadIdx.x;
    const int wave = tid >> 6, lane = tid & 63;
    const int m_ = lane & 15, quad = lane >> 4;
    const int bh = blockIdx.x >> 5, qr = blockIdx.x & 31;
    const int b = bh >> 4, h = bh & 15;

    int r0 = qr - 3; if (r0 < 0) r0 = 0;
    int r1 = qr + 3; if (r1 > 31) r1 = 31;
    const int nrows = r1 - r0 + 1;
    const int limit = 8 + nrows * 32;

    const ushort_t* Qg  = Qb + ((long)bh * NTOK + 8 + qr * 32) * 64;
    const ushort_t* Kg  = Kb + (long)bh * NTOK * 64;
    const ushort_t* Vtg = Vt + (long)bh * 64 * NTOK;

    if (tid < 32) l_s[tid] = 0.f;

    bf16x8 af[2][2];
    #pragma unroll
    for (int mt = 0; mt < 2; ++mt)
        #pragma unroll
        for (int ks = 0; ks < 2; ++ks)
            af[mt][ks] = *(const bf16x8*)(Qg + (mt * 16 + m_) * 64 + ks * 32 + quad * 8);

    for (int c = tid; c < limit * 8; c += 256) {
        const int slot = c >> 3, c8 = (c & 7) * 8;
        const int tok = slot + (slot >= 8 ? r0 * 32 : 0);
        *(bf16x8*)&KP_s[slot * 72 + c8] = *(const bf16x8*)(Kg + (long)tok * 64 + c8);
    }
    __syncthreads();

    const int nb = wave * 64;
    bf16x8 bfr[4][2];
    #pragma unroll
    for (int nt = 0; nt < 4; ++nt)
        #pragma unroll
        for (int ks = 0; ks < 2; ++ks)
            bfr[nt][ks] = *(const bf16x8*)&KP_s[(nb + nt * 16 + m_) * 72 + ks * 32 + quad * 8];

    f32x4 sacc[2][4] = {};
    #pragma unroll
    for (int mt = 0; mt < 2; ++mt)
        #pragma unroll
        for (int nt = 0; nt < 4; ++nt) {
            sacc[mt][nt] = __builtin_amdgcn_mfma_f32_16x16x32_bf16(
                af[mt][0], bfr[nt][0], sacc[mt][nt], 0, 0, 0);
            sacc[mt][nt] = __builtin_amdgcn_mfma_f32_16x16x32_bf16(
                af[mt][1], bfr[nt][1], sacc[mt][nt], 0, 0, 0);
        }
    __syncthreads();

    #pragma unroll
    for (int mt = 0; mt < 2; ++mt)
        #pragma unroll
        for (int nt = 0; nt < 4; ++nt) {
            const int slot = nb + nt * 16 + m_;
            const int kc = (slot - 8) & 31;
            #pragma unroll
            for (int reg = 0; reg < 4; ++reg) {
                const int qm = mt * 16 + quad * 4 + reg;
                const bool val = (slot < 8) ||
                    ((slot < limit) && ((unsigned)(kc - qm + 3) <= 6u));
                const float s = sacc[mt][nt][reg];
                const float p = val ? __expf(s * 0.125f) : 0.f;
                KP_s[qm * 280 + slot] = f2bf(p);
                float rs = p;
                #pragma unroll
                for (int off = 1; off < 16; off <<= 1) rs += __shfl_xor(rs, off);
                if (m_ == 0) atomicAdd(&l_s[qm], rs);
            }
        }
    __syncthreads();

    {
        const int d0 = wave * 16;
        f32x4 oacc[2] = {};
        #pragma unroll
        for (int ks = 0; ks < 8; ++ks) {
            const int slot0 = ks * 32 + quad * 8;
            int tok0;
            if (slot0 >= limit) tok0 = 0;
            else if (slot0 < 8) tok0 = slot0;
            else tok0 = 8 + r0 * 32 + (slot0 - 8);
            const bf16x8 bv = *(const bf16x8*)(Vtg + (long)(d0 + m_) * NTOK + tok0);
            #pragma unroll
            for (int mt = 0; mt < 2; ++mt) {
                const bf16x8 ap = *(const bf16x8*)&KP_s[(mt * 16 + m_) * 280 + ks * 32 + quad * 8];
                oacc[mt] = __builtin_amdgcn_mfma_f32_16x16x32_bf16(ap, bv, oacc[mt], 0, 0, 0);
            }
        }
        #pragma unroll
        for (int mt = 0; mt < 2; ++mt)
            #pragma unroll
            for (int reg = 0; reg < 4; ++reg) {
                const int qm = mt * 16 + quad * 4 + reg;
                const int tok = 8 + qr * 32 + qm;
                const float rl = l_s[qm];
                AO[((long)(b * NTOK + tok)) * DIMC + h * 64 + wave * 16 + m_] =
                    f2bf(oacc[mt][reg] / rl);
            }
    }
}

// ---------------------------------------------------------------------------
// Special-token attention (unchanged from round 7).
// ---------------------------------------------------------------------------
__global__ __launch_bounds__(256) void attn_special_kernel(
    const ushort_t* __restrict__ Qb, const ushort_t* __restrict__ Kb,
    const ushort_t* __restrict__ Vt, ushort_t* __restrict__ AO)
{
    __shared__ __align__(16) ushort_t Q_s[16 * 72];
    __shared__ __align__(16) ushort_t K_s[256 * 72];
    __shared__ __align__(16) ushort_t P_s[16 * 280];
    __shared__ float l_s[16];

    const int tid = threadIdx.x;
    const int wave = tid >> 6, lane = tid & 63;
    const int m_ = lane & 15, quad = lane >> 4;
    const int bh = blockIdx.x;
    const int b = bh >> 4, h = bh & 15;

    const ushort_t* Kg  = Kb + (long)bh * NTOK * 64;
    const ushort_t* Vtg = Vt + (long)bh * 64 * NTOK;

    if (tid < 16) l_s[tid] = 0.f;
    if (tid < 128) {
        const int row = tid >> 3, c8 = (tid & 7) * 8;
        bf16x8 v;
        if (row < 8) {
            v = *(const bf16x8*)(Qb + ((long)bh * NTOK + row) * 64 + c8);
        } else {
            #pragma unroll
            for (int e = 0; e < 8; ++e) v[e] = (__bf16)0.f;
        }
        *(bf16x8*)&Q_s[row * 72 + c8] = v;
    }

    const int d0 = wave * 16;
    const int nb = wave * 64;
    f32x4 oacc = {};

    for (int ch = 0; ch < 5; ++ch) {
        const int tok0 = ch * 256;
        const int limit = (NTOK - tok0 < 256) ? (NTOK - tok0) : 256;
        __syncthreads();
        for (int c = tid; c < limit * 8; c += 256) {
            const int slot = c >> 3, c8 = (c & 7) * 8;
            *(bf16x8*)&K_s[slot * 72 + c8] =
                *(const bf16x8*)(Kg + (long)(tok0 + slot) * 64 + c8);
        }
        __syncthreads();

        {
            bf16x8 af[2], bfr[4][2];
            #pragma unroll
            for (int ks = 0; ks < 2; ++ks)
                af[ks] = *(const bf16x8*)&Q_s[m_ * 72 + ks * 32 + quad * 8];
            #pragma unroll
            for (int nt = 0; nt < 4; ++nt)
                #pragma unroll
                for (int ks = 0; ks < 2; ++ks)
                    bfr[nt][ks] = *(const bf16x8*)&K_s[(nb + nt * 16 + m_) * 72 + ks * 32 + quad * 8];
            f32x4 sacc[4] = {};
            #pragma unroll
            for (int nt = 0; nt < 4; ++nt) {
                sacc[nt] = __builtin_amdgcn_mfma_f32_16x16x32_bf16(af[0], bfr[nt][0], sacc[nt], 0, 0, 0);
                sacc[nt] = __builtin_amdgcn_mfma_f32_16x16x32_bf16(af[1], bfr[nt][1], sacc[nt], 0, 0, 0);
            }
            #pragma unroll
            for (int nt = 0; nt < 4; ++nt) {
                const int slot = nb + nt * 16 + m_;
                const bool val = (slot < limit);
                #pragma unroll
                for (int reg = 0; reg < 4; ++reg) {
                    const int qm = quad * 4 + reg;
                    const float p = val ? __expf(sacc[nt][reg] * 0.125f) : 0.f;
                    P_s[qm * 280 + slot] = f2bf(p);
                    float rs = p;
                    #pragma unroll
                    for (int off = 1; off < 16; off <<= 1) rs += __shfl_xor(rs, off);
                    if (m_ == 0 && qm < 8) atomicAdd(&l_s[qm], rs);
                }
            }
        }
        __syncthreads();

        #pragma unroll
        for (int ks = 0; ks < 8; ++ks) {
            const int slot0 = ks * 32 + quad * 8;
            const int tok = tok0 + ((slot0 < limit) ? slot0 : 0);
            const bf16x8 bv = *(const bf16x8*)(Vtg + (long)(d0 + m_) * NTOK + tok);
            const bf16x8 ap = *(const bf16x8*)&P_s[m_ * 280 + ks * 32 + quad * 8];
            oacc = __builtin_amdgcn_mfma_f32_16x16x32_bf16(ap, bv, oacc, 0, 0, 0);
        }
    }
    __syncthreads();

    #pragma unroll
    for (int reg = 0; reg < 4; ++reg) {
        const int qm = quad * 4 + reg;
        if (qm < 8) {
            AO[((long)(b * NTOK + qm)) * DIMC + h * 64 + d0 + m_] =
                f2bf(oacc[reg] / l_s[qm]);
        }
    }
}

extern "C" void kernel_launch(void* const* d_in, const int* in_sizes, int n_in,
                              void* d_out, int out_size, void* d_ws, size_t ws_size,
                              hipStream_t stream) {
    const float* X    = (const float*)d_in[0];
    const float* fc   = (const float*)d_in[1];
    const float* fs   = (const float*)d_in[2];
    const float* qkvw = (const float*)d_in[3];
    const float* outw = (const float*)d_in[4];
    const float* nqw  = (const float*)d_in[5];
    const float* nkw  = (const float*)d_in[6];

    ushort_t* Qb  = (ushort_t*)d_ws;     // 16.9 MB each
    ushort_t* Kb  = Qb + QKV_ELEMS;
    ushort_t* Vt  = Kb + QKV_ELEMS;      // dim-major [bh][d][n]
    ushort_t* AO  = Vt + QKV_ELEMS;
    ushort_t* Xb  = AO + QKV_ELEMS;      // bf16 X (16.9 MB)
    ushort_t* Wqb = Xb + XE;             // bf16 qkv_w (6.3 MB)
    ushort_t* Wob = Wqb + QWE;           // bf16 out_w (2.1 MB)
    float* Out = (float*)d_out;

    cvt_kernel<<<6176, 256, 0, stream>>>(X, qkvw, outw, Xb, Wqb, Wob);
    // Q,K parts (swapped MFMA -> d-contiguous 8B stores)
    gemm_kernel<0, true><<<dim3(16, 65), 256, 0, stream>>>(Xb, Wqb, Qb, nullptr, 0);
    // V part (unswapped -> n-contiguous 8B stores into dim-major Vt)
    gemm_kernel<0, false><<<dim3(8, 65), 256, 0, stream>>>(Xb, Wqb, Qb, nullptr, 2048);
    rope_kernel<<<66048, 256, 0, stream>>>(Qb, Kb, fc, fs, nqw, nkw);
    attn_patch_kernel<<<4096, 256, 0, stream>>>(Qb, Kb, Vt, AO);
    attn_special_kernel<<<128, 256, 0, stream>>>(Qb, Kb, Vt, AO);
    // out proj (swapped -> o-contiguous float4 stores)
    gemm_kernel<1, true><<<dim3(8, 65), 256, 0, stream>>>(AO, Wob, nullptr, Out, 0);
}

// Round 10
// 362.552 us; speedup vs baseline: 1.0755x; 1.0094x over previous
//
#include <hip/hip_runtime.h>
#include <hip/hip_bf16.h>

typedef unsigned short ushort_t;
typedef __bf16 bf16x8 __attribute__((ext_vector_type(8)));
typedef float f32x4 __attribute__((ext_vector_type(4)));
typedef float f32x8 __attribute__((ext_vector_type(8)));

#define NTOK 1032
#define NROWS 8256       // B*N = 8*1032
#define DIMC 1024
#define QKV_ELEMS 8454144  // 8*16*1032*64 elements per tensor
#define XE 8454144         // X elements (8256*1024)
#define QWE 3145728        // qkv_w elements (3072*1024)
#define OWE 1048576        // out_w elements (1024*1024)

__device__ __forceinline__ float bf2f(ushort_t u) {
    union { unsigned int i; float f; } v; v.i = ((unsigned int)u) << 16; return v.f;
}
__device__ __forceinline__ ushort_t f2bf(float f) {
    union { float f; unsigned int i; } v; v.f = f;
    unsigned int r = v.i + 0x7fffu + ((v.i >> 16) & 1u);
    return (ushort_t)(r >> 16);
}
__device__ __forceinline__ bf16x8 cvt8(const float* p) {
    const float4 a = *(const float4*)p;
    const float4 b = *(const float4*)(p + 4);
    bf16x8 r;
    r[0] = (__bf16)a.x; r[1] = (__bf16)a.y; r[2] = (__bf16)a.z; r[3] = (__bf16)a.w;
    r[4] = (__bf16)b.x; r[5] = (__bf16)b.y; r[6] = (__bf16)b.z; r[7] = (__bf16)b.w;
    return r;
}
__device__ __forceinline__ void load_lds16(const ushort_t* g, ushort_t* l) {
    __builtin_amdgcn_global_load_lds(
        (const __attribute__((address_space(1))) unsigned int*)g,
        (__attribute__((address_space(3))) unsigned int*)l, 16, 0, 0);
}

// ---------------------------------------------------------------------------
// fp32 -> bf16 pre-conversion of X, qkv_w, out_w (RNE).
// ---------------------------------------------------------------------------
__global__ __launch_bounds__(256) void cvt_kernel(
    const float* __restrict__ X, const float* __restrict__ Wq,
    const float* __restrict__ Wo,
    ushort_t* __restrict__ Xb, ushort_t* __restrict__ Wqb,
    ushort_t* __restrict__ Wob)
{
    const long i8 = ((long)blockIdx.x * 256 + threadIdx.x) * 8;
    const float* src;
    ushort_t* dst;
    long off;
    if (i8 < XE)            { src = X;  dst = Xb;  off = i8; }
    else if (i8 < XE + QWE) { src = Wq; dst = Wqb; off = i8 - XE; }
    else                    { src = Wo; dst = Wob; off = i8 - XE - QWE; }
    *(bf16x8*)(dst + off) = cvt8(src + off);
}

// ---------------------------------------------------------------------------
// GEMM (round-9 version: m97 K-loop + operand-swap epilogues).
// ---------------------------------------------------------------------------
template<int MODE, bool SWAP>
__global__ __launch_bounds__(256) void gemm_kernel(
    const ushort_t* __restrict__ A, const ushort_t* __restrict__ W,
    ushort_t* __restrict__ QKV, float* __restrict__ Out, int n_base)
{
    __shared__ __align__(16) ushort_t As[128 * 32];
    __shared__ __align__(16) ushort_t Bs[128 * 32];
    const int tid  = threadIdx.x;
    const int wave = tid >> 6, lane = tid & 63;
    const int m0 = blockIdx.y * 128;
    const int n0 = n_base + blockIdx.x * 128;

    f32x4 acc[4][4] = {};

    const int s0 = tid, s1 = tid + 256;
    int ar0 = m0 + (s0 >> 2); if (ar0 > NROWS - 1) ar0 = NROWS - 1;
    int ar1 = m0 + (s1 >> 2); if (ar1 > NROWS - 1) ar1 = NROWS - 1;
    const int br0 = n0 + (s0 >> 2);
    const int br1 = n0 + (s1 >> 2);
    const int kc0 = (s0 & 3) * 8, kc1 = (s1 & 3) * 8;

    const ushort_t* ga0 = A + (long)ar0 * DIMC + kc0;
    const ushort_t* ga1 = A + (long)ar1 * DIMC + kc1;
    const ushort_t* gw0 = W + (long)br0 * DIMC + kc0;
    const ushort_t* gw1 = W + (long)br1 * DIMC + kc1;
    ushort_t* la0 = &As[s0 * 8];
    ushort_t* la1 = &As[s1 * 8];
    ushort_t* lb0 = &Bs[s0 * 8];
    ushort_t* lb1 = &Bs[s1 * 8];

    const int wm = (wave >> 1) * 64, wn = (wave & 1) * 64;
    const int fr = lane & 15, fk = (lane >> 4) * 8;

    for (int k0 = 0; k0 < DIMC; k0 += 32) {
        load_lds16(ga0 + k0, la0);
        load_lds16(ga1 + k0, la1);
        load_lds16(gw0 + k0, lb0);
        load_lds16(gw1 + k0, lb1);
        __syncthreads();

        bf16x8 af[4], bfr[4];
        #pragma unroll
        for (int mi = 0; mi < 4; ++mi)
            af[mi] = *(const bf16x8*)&As[(wm + mi * 16 + fr) * 32 + fk];
        #pragma unroll
        for (int ni = 0; ni < 4; ++ni)
            bfr[ni] = *(const bf16x8*)&Bs[(wn + ni * 16 + fr) * 32 + fk];
        #pragma unroll
        for (int mi = 0; mi < 4; ++mi)
            #pragma unroll
            for (int ni = 0; ni < 4; ++ni) {
                if (SWAP)
                    acc[mi][ni] = __builtin_amdgcn_mfma_f32_16x16x32_bf16(
                        bfr[ni], af[mi], acc[mi][ni], 0, 0, 0);
                else
                    acc[mi][ni] = __builtin_amdgcn_mfma_f32_16x16x32_bf16(
                        af[mi], bfr[ni], acc[mi][ni], 0, 0, 0);
            }
        __syncthreads();
    }

    const int col = lane & 15, rb = (lane >> 4) * 4;

    if (MODE == 0 && SWAP) {
        const int part = n0 >> 10;
        #pragma unroll
        for (int mi = 0; mi < 4; ++mi) {
            const int m = m0 + wm + mi * 16 + col;
            if (m < NROWS) {
                const int bb = m / NTOK, n = m - bb * NTOK;
                #pragma unroll
                for (int ni = 0; ni < 4; ++ni) {
                    const int rem = (n0 & 1023) + wn + ni * 16 + rb;
                    const int hg = rem >> 6, d = rem & 63;
                    ushort4 pk;
                    pk.x = f2bf(acc[mi][ni][0]);
                    pk.y = f2bf(acc[mi][ni][1]);
                    pk.z = f2bf(acc[mi][ni][2]);
                    pk.w = f2bf(acc[mi][ni][3]);
                    *(ushort4*)(QKV + (long)part * QKV_ELEMS +
                        ((long)(bb * 16 + hg) * NTOK + n) * 64 + d) = pk;
                }
            }
        }
    } else if (MODE == 0) {
        #pragma unroll
        for (int ni = 0; ni < 4; ++ni) {
            const int o = n0 + wn + ni * 16 + col;
            const int rem = o & 1023;
            const int hg = rem >> 6, d = rem & 63;
            #pragma unroll
            for (int mi = 0; mi < 4; ++mi) {
                const int mb = m0 + wm + mi * 16 + rb;
                if (mb < NROWS) {
                    const int bb = mb / NTOK, n = mb - bb * NTOK;
                    ushort4 pk;
                    pk.x = f2bf(acc[mi][ni][0]);
                    pk.y = f2bf(acc[mi][ni][1]);
                    pk.z = f2bf(acc[mi][ni][2]);
                    pk.w = f2bf(acc[mi][ni][3]);
                    *(ushort4*)(QKV + 2L * QKV_ELEMS +
                        ((long)((bb * 16 + hg) * 64 + d)) * NTOK + n) = pk;
                }
            }
        }
    } else {
        #pragma unroll
        for (int mi = 0; mi < 4; ++mi) {
            const int m = m0 + wm + mi * 16 + col;
            if (m < NROWS) {
                #pragma unroll
                for (int ni = 0; ni < 4; ++ni) {
                    const int o = n0 + wn + ni * 16 + rb;
                    float4 pk;
                    pk.x = acc[mi][ni][0];
                    pk.y = acc[mi][ni][1];
                    pk.z = acc[mi][ni][2];
                    pk.w = acc[mi][ni][3];
                    *(float4*)(Out + (long)m * DIMC + o) = pk;
                }
            }
        }
    }
}

// ---------------------------------------------------------------------------
// RMSNorm + RoPE, one THREAD per (tensor,bh,token): 128B contiguous vector
// loads, in-thread RMS (no shuffles), rotate-half in-register (chunk c ^ 4).
// 1032 blocks x 256 = 264192 = 2*132096 exactly; tensor uniform per block.
// ---------------------------------------------------------------------------
__global__ __launch_bounds__(256) void rope_kernel(
    ushort_t* __restrict__ Qb, ushort_t* __restrict__ Kb,
    const float* __restrict__ cosb, const float* __restrict__ sinb,
    const float* __restrict__ wq, const float* __restrict__ wk)
{
    __shared__ float wsh[64];
    const int idx = blockIdx.x * 256 + threadIdx.x;
    const int tensor = (idx >= 132096) ? 1 : 0;
    const int r = idx - tensor * 132096;
    const int n = r % NTOK;
    if (threadIdx.x < 64) wsh[threadIdx.x] = (tensor ? wk : wq)[threadIdx.x];
    __syncthreads();

    ushort_t* base = (tensor ? Kb : Qb) + (long)r * 64;
    bf16x8 xc[8];
    #pragma unroll
    for (int c = 0; c < 8; ++c) xc[c] = *(const bf16x8*)(base + c * 8);

    float ss = 0.f;
    #pragma unroll
    for (int c = 0; c < 8; ++c) {
        const f32x8 xf = __builtin_convertvector(xc[c], f32x8);
        #pragma unroll
        for (int e = 0; e < 8; ++e) ss += xf[e] * xf[e];
    }
    const float rms = rsqrtf(ss * (1.0f / 64.0f) + 1e-6f);

    const float* cosp = cosb + n * 64;
    const float* sinp = sinb + n * 64;
    #pragma unroll
    for (int c = 0; c < 8; ++c) {
        const f32x8 xf = __builtin_convertvector(xc[c], f32x8);
        const f32x8 pf = __builtin_convertvector(xc[c ^ 4], f32x8);
        const float sgn = (c < 4) ? -1.f : 1.f;
        bf16x8 o8;
        #pragma unroll
        for (int e = 0; e < 8; ++e) {
            const float xn  = xf[e] * rms * wsh[c * 8 + e];
            const float rot = sgn * pf[e] * rms * wsh[(c ^ 4) * 8 + e];
            o8[e] = (__bf16)(xn * cosp[c * 8 + e] + rot * sinp[c * 8 + e]);
        }
        *(bf16x8*)(base + c * 8) = o8;
    }
}

// ---------------------------------------------------------------------------
// Merged attention. Blocks [0,4096): patch, XCD-swizzled (bh = blk&127 so all
// 32 q-rows of a bh land on one XCD; 128%8==0). Blocks [4096,4224): special
// (bh = blk-4096 -> same XCD as its patch siblings), patch-style K->P overlay
// in the shared KP_s, Q/V direct from global.
// ---------------------------------------------------------------------------
__global__ __launch_bounds__(256) void attn_kernel(
    const ushort_t* __restrict__ Qb, const ushort_t* __restrict__ Kb,
    const ushort_t* __restrict__ Vt, ushort_t* __restrict__ AO)
{
    __shared__ __align__(16) ushort_t KP_s[256 * 72];  // K (stride 72) then P (stride 280)
    __shared__ float l_s[32];

    const int tid = threadIdx.x;
    const int wave = tid >> 6, lane = tid & 63;
    const int m_ = lane & 15, quad = lane >> 4;
    const int nb = wave * 64;
    const int d0 = wave * 16;

    if (blockIdx.x < 4096) {
        // ================= PATCH =================
        const int bh = blockIdx.x & 127, qr = blockIdx.x >> 7;
        const int b = bh >> 4, h = bh & 15;

        int r0 = qr - 3; if (r0 < 0) r0 = 0;
        int r1 = qr + 3; if (r1 > 31) r1 = 31;
        const int limit = 8 + (r1 - r0 + 1) * 32;

        const ushort_t* Qg  = Qb + ((long)bh * NTOK + 8 + qr * 32) * 64;
        const ushort_t* Kg  = Kb + (long)bh * NTOK * 64;
        const ushort_t* Vtg = Vt + (long)bh * 64 * NTOK;

        if (tid < 32) l_s[tid] = 0.f;

        bf16x8 af[2][2];
        #pragma unroll
        for (int mt = 0; mt < 2; ++mt)
            #pragma unroll
            for (int ks = 0; ks < 2; ++ks)
                af[mt][ks] = *(const bf16x8*)(Qg + (mt * 16 + m_) * 64 + ks * 32 + quad * 8);

        for (int c = tid; c < limit * 8; c += 256) {
            const int slot = c >> 3, c8 = (c & 7) * 8;
            const int tok = slot + (slot >= 8 ? r0 * 32 : 0);
            *(bf16x8*)&KP_s[slot * 72 + c8] = *(const bf16x8*)(Kg + (long)tok * 64 + c8);
        }
        __syncthreads();

        bf16x8 bfr[4][2];
        #pragma unroll
        for (int nt = 0; nt < 4; ++nt)
            #pragma unroll
            for (int ks = 0; ks < 2; ++ks)
                bfr[nt][ks] = *(const bf16x8*)&KP_s[(nb + nt * 16 + m_) * 72 + ks * 32 + quad * 8];

        f32x4 sacc[2][4] = {};
        #pragma unroll
        for (int mt = 0; mt < 2; ++mt)
            #pragma unroll
            for (int nt = 0; nt < 4; ++nt) {
                sacc[mt][nt] = __builtin_amdgcn_mfma_f32_16x16x32_bf16(
                    af[mt][0], bfr[nt][0], sacc[mt][nt], 0, 0, 0);
                sacc[mt][nt] = __builtin_amdgcn_mfma_f32_16x16x32_bf16(
                    af[mt][1], bfr[nt][1], sacc[mt][nt], 0, 0, 0);
            }
        __syncthreads();   // K fragment reads done -> safe to overwrite with P

        #pragma unroll
        for (int mt = 0; mt < 2; ++mt)
            #pragma unroll
            for (int nt = 0; nt < 4; ++nt) {
                const int slot = nb + nt * 16 + m_;
                const int kc = (slot - 8) & 31;
                #pragma unroll
                for (int reg = 0; reg < 4; ++reg) {
                    const int qm = mt * 16 + quad * 4 + reg;
                    const bool val = (slot < 8) ||
                        ((slot < limit) && ((unsigned)(kc - qm + 3) <= 6u));
                    const float p = val ? __expf(sacc[mt][nt][reg] * 0.125f) : 0.f;
                    KP_s[qm * 280 + slot] = f2bf(p);
                    float rs = p;
                    #pragma unroll
                    for (int off = 1; off < 16; off <<= 1) rs += __shfl_xor(rs, off);
                    if (m_ == 0) atomicAdd(&l_s[qm], rs);
                }
            }
        __syncthreads();

        f32x4 oacc[2] = {};
        #pragma unroll
        for (int ks = 0; ks < 8; ++ks) {
            const int slot0 = ks * 32 + quad * 8;
            int tok0;
            if (slot0 >= limit) tok0 = 0;
            else if (slot0 < 8) tok0 = slot0;
            else tok0 = 8 + r0 * 32 + (slot0 - 8);
            const bf16x8 bv = *(const bf16x8*)(Vtg + (long)(d0 + m_) * NTOK + tok0);
            #pragma unroll
            for (int mt = 0; mt < 2; ++mt) {
                const bf16x8 ap = *(const bf16x8*)&KP_s[(mt * 16 + m_) * 280 + ks * 32 + quad * 8];
                oacc[mt] = __builtin_amdgcn_mfma_f32_16x16x32_bf16(ap, bv, oacc[mt], 0, 0, 0);
            }
        }
        #pragma unroll
        for (int mt = 0; mt < 2; ++mt)
            #pragma unroll
            for (int reg = 0; reg < 4; ++reg) {
                const int qm = mt * 16 + quad * 4 + reg;
                const int tok = 8 + qr * 32 + qm;
                AO[((long)(b * NTOK + tok)) * DIMC + h * 64 + d0 + m_] =
                    f2bf(oacc[mt][reg] / l_s[qm]);
            }
    } else {
        // ================= SPECIAL =================
        const int bh = blockIdx.x - 4096;
        const int b = bh >> 4, h = bh & 15;
        const ushort_t* Kg  = Kb + (long)bh * NTOK * 64;
        const ushort_t* Vtg = Vt + (long)bh * 64 * NTOK;

        if (tid < 16) l_s[tid] = 0.f;

        // Q fragments direct (rows >= 8 are zero padding)
        bf16x8 afs[2];
        if (m_ < 8) {
            #pragma unroll
            for (int ks = 0; ks < 2; ++ks)
                afs[ks] = *(const bf16x8*)(Qb + ((long)bh * NTOK + m_) * 64 + ks * 32 + quad * 8);
        } else {
            #pragma unroll
            for (int ks = 0; ks < 2; ++ks)
                #pragma unroll
                for (int e = 0; e < 8; ++e) afs[ks][e] = (__bf16)0.f;
        }

        f32x4 oacc = {};
        for (int ch = 0; ch < 5; ++ch) {
            const int tok0 = ch * 256;
            const int limit = (NTOK - tok0 < 256) ? (NTOK - tok0) : 256;
            __syncthreads();   // prior PV's P reads complete before K restage
            for (int c = tid; c < limit * 8; c += 256) {
                const int slot = c >> 3, c8 = (c & 7) * 8;
                *(bf16x8*)&KP_s[slot * 72 + c8] =
                    *(const bf16x8*)(Kg + (long)(tok0 + slot) * 64 + c8);
            }
            __syncthreads();

            bf16x8 bfr[4][2];
            #pragma unroll
            for (int nt = 0; nt < 4; ++nt)
                #pragma unroll
                for (int ks = 0; ks < 2; ++ks)
                    bfr[nt][ks] = *(const bf16x8*)&KP_s[(nb + nt * 16 + m_) * 72 + ks * 32 + quad * 8];
            f32x4 sacc[4] = {};
            #pragma unroll
            for (int nt = 0; nt < 4; ++nt) {
                sacc[nt] = __builtin_amdgcn_mfma_f32_16x16x32_bf16(afs[0], bfr[nt][0], sacc[nt], 0, 0, 0);
                sacc[nt] = __builtin_amdgcn_mfma_f32_16x16x32_bf16(afs[1], bfr[nt][1], sacc[nt], 0, 0, 0);
            }
            __syncthreads();   // K fragment reads done -> overlay P

            #pragma unroll
            for (int nt = 0; nt < 4; ++nt) {
                const int slot = nb + nt * 16 + m_;
                const bool val = (slot < limit);
                #pragma unroll
                for (int reg = 0; reg < 4; ++reg) {
                    const int qm = quad * 4 + reg;
                    const float p = val ? __expf(sacc[nt][reg] * 0.125f) : 0.f;
                    KP_s[qm * 280 + slot] = f2bf(p);
                    float rs = p;
                    #pragma unroll
                    for (int off = 1; off < 16; off <<= 1) rs += __shfl_xor(rs, off);
                    if (m_ == 0 && qm < 8) atomicAdd(&l_s[qm], rs);
                }
            }
            __syncthreads();

            #pragma unroll
            for (int ks = 0; ks < 8; ++ks) {
                const int slot0 = ks * 32 + quad * 8;
                const int tok = tok0 + ((slot0 < limit) ? slot0 : 0);
                const bf16x8 bv = *(const bf16x8*)(Vtg + (long)(d0 + m_) * NTOK + tok);
                const bf16x8 ap = *(const bf16x8*)&KP_s[m_ * 280 + ks * 32 + quad * 8];
                oacc = __builtin_amdgcn_mfma_f32_16x16x32_bf16(ap, bv, oacc, 0, 0, 0);
            }
        }
        __syncthreads();

        #pragma unroll
        for (int reg = 0; reg < 4; ++reg) {
            const int qm = quad * 4 + reg;
            if (qm < 8) {
                AO[((long)(b * NTOK + qm)) * DIMC + h * 64 + d0 + m_] =
                    f2bf(oacc[reg] / l_s[qm]);
            }
        }
    }
}

extern "C" void kernel_launch(void* const* d_in, const int* in_sizes, int n_in,
                              void* d_out, int out_size, void* d_ws, size_t ws_size,
                              hipStream_t stream) {
    const float* X    = (const float*)d_in[0];
    const float* fc   = (const float*)d_in[1];
    const float* fs   = (const float*)d_in[2];
    const float* qkvw = (const float*)d_in[3];
    const float* outw = (const float*)d_in[4];
    const float* nqw  = (const float*)d_in[5];
    const float* nkw  = (const float*)d_in[6];

    ushort_t* Qb  = (ushort_t*)d_ws;     // 16.9 MB each
    ushort_t* Kb  = Qb + QKV_ELEMS;
    ushort_t* Vt  = Kb + QKV_ELEMS;      // dim-major [bh][d][n]
    ushort_t* AO  = Vt + QKV_ELEMS;
    ushort_t* Xb  = AO + QKV_ELEMS;      // bf16 X (16.9 MB)
    ushort_t* Wqb = Xb + XE;             // bf16 qkv_w (6.3 MB)
    ushort_t* Wob = Wqb + QWE;           // bf16 out_w (2.1 MB)
    float* Out = (float*)d_out;

    cvt_kernel<<<6176, 256, 0, stream>>>(X, qkvw, outw, Xb, Wqb, Wob);
    gemm_kernel<0, true><<<dim3(16, 65), 256, 0, stream>>>(Xb, Wqb, Qb, nullptr, 0);
    gemm_kernel<0, false><<<dim3(8, 65), 256, 0, stream>>>(Xb, Wqb, Qb, nullptr, 2048);
    rope_kernel<<<1032, 256, 0, stream>>>(Qb, Kb, fc, fs, nqw, nkw);
    attn_kernel<<<4224, 256, 0, stream>>>(Qb, Kb, Vt, AO);
    gemm_kernel<1, true><<<dim3(8, 65), 256, 0, stream>>>(AO, Wob, nullptr, Out, 0);
}

// Round 11
// 319.745 us; speedup vs baseline: 1.2195x; 1.1339x over previous
//
#include <hip/hip_runtime.h>
#include <hip/hip_bf16.h>

typedef unsigned short ushort_t;
typedef __bf16 bf16x8 __attribute__((ext_vector_type(8)));
typedef float f32x4 __attribute__((ext_vector_type(4)));
typedef float f32x8 __attribute__((ext_vector_type(8)));

#define NTOK 1032
#define NROWS 8256       // B*N = 8*1032
#define DIMC 1024
#define QKV_ELEMS 8454144  // 8*16*1032*64 elements per tensor
#define XE 8454144         // X elements (8256*1024)
#define QWE 3145728        // qkv_w elements (3072*1024)
#define OWE 1048576        // out_w elements (1024*1024)

__device__ __forceinline__ float bf2f(ushort_t u) {
    union { unsigned int i; float f; } v; v.i = ((unsigned int)u) << 16; return v.f;
}
__device__ __forceinline__ ushort_t f2bf(float f) {
    union { float f; unsigned int i; } v; v.f = f;
    unsigned int r = v.i + 0x7fffu + ((v.i >> 16) & 1u);
    return (ushort_t)(r >> 16);
}
__device__ __forceinline__ bf16x8 cvt8(const float* p) {
    const float4 a = *(const float4*)p;
    const float4 b = *(const float4*)(p + 4);
    bf16x8 r;
    r[0] = (__bf16)a.x; r[1] = (__bf16)a.y; r[2] = (__bf16)a.z; r[3] = (__bf16)a.w;
    r[4] = (__bf16)b.x; r[5] = (__bf16)b.y; r[6] = (__bf16)b.z; r[7] = (__bf16)b.w;
    return r;
}
__device__ __forceinline__ void load_lds16(const ushort_t* g, ushort_t* l) {
    __builtin_amdgcn_global_load_lds(
        (const __attribute__((address_space(1))) unsigned int*)g,
        (__attribute__((address_space(3))) unsigned int*)l, 16, 0, 0);
}

// ---------------------------------------------------------------------------
// fp32 -> bf16 pre-conversion of X, qkv_w, out_w (RNE).
// ---------------------------------------------------------------------------
__global__ __launch_bounds__(256) void cvt_kernel(
    const float* __restrict__ X, const float* __restrict__ Wq,
    const float* __restrict__ Wo,
    ushort_t* __restrict__ Xb, ushort_t* __restrict__ Wqb,
    ushort_t* __restrict__ Wob)
{
    const long i8 = ((long)blockIdx.x * 256 + threadIdx.x) * 8;
    const float* src;
    ushort_t* dst;
    long off;
    if (i8 < XE)            { src = X;  dst = Xb;  off = i8; }
    else if (i8 < XE + QWE) { src = Wq; dst = Wqb; off = i8 - XE; }
    else                    { src = Wo; dst = Wob; off = i8 - XE - QWE; }
    *(bf16x8*)(dst + off) = cvt8(src + off);
}

// ---------------------------------------------------------------------------
// GEMM (m97 K-loop + operand-swap epilogues). Unchanged from round 10.
// ---------------------------------------------------------------------------
template<int MODE, bool SWAP>
__global__ __launch_bounds__(256) void gemm_kernel(
    const ushort_t* __restrict__ A, const ushort_t* __restrict__ W,
    ushort_t* __restrict__ QKV, float* __restrict__ Out, int n_base)
{
    __shared__ __align__(16) ushort_t As[128 * 32];
    __shared__ __align__(16) ushort_t Bs[128 * 32];
    const int tid  = threadIdx.x;
    const int wave = tid >> 6, lane = tid & 63;
    const int m0 = blockIdx.y * 128;
    const int n0 = n_base + blockIdx.x * 128;

    f32x4 acc[4][4] = {};

    const int s0 = tid, s1 = tid + 256;
    int ar0 = m0 + (s0 >> 2); if (ar0 > NROWS - 1) ar0 = NROWS - 1;
    int ar1 = m0 + (s1 >> 2); if (ar1 > NROWS - 1) ar1 = NROWS - 1;
    const int br0 = n0 + (s0 >> 2);
    const int br1 = n0 + (s1 >> 2);
    const int kc0 = (s0 & 3) * 8, kc1 = (s1 & 3) * 8;

    const ushort_t* ga0 = A + (long)ar0 * DIMC + kc0;
    const ushort_t* ga1 = A + (long)ar1 * DIMC + kc1;
    const ushort_t* gw0 = W + (long)br0 * DIMC + kc0;
    const ushort_t* gw1 = W + (long)br1 * DIMC + kc1;
    ushort_t* la0 = &As[s0 * 8];
    ushort_t* la1 = &As[s1 * 8];
    ushort_t* lb0 = &Bs[s0 * 8];
    ushort_t* lb1 = &Bs[s1 * 8];

    const int wm = (wave >> 1) * 64, wn = (wave & 1) * 64;
    const int fr = lane & 15, fk = (lane >> 4) * 8;

    for (int k0 = 0; k0 < DIMC; k0 += 32) {
        load_lds16(ga0 + k0, la0);
        load_lds16(ga1 + k0, la1);
        load_lds16(gw0 + k0, lb0);
        load_lds16(gw1 + k0, lb1);
        __syncthreads();

        bf16x8 af[4], bfr[4];
        #pragma unroll
        for (int mi = 0; mi < 4; ++mi)
            af[mi] = *(const bf16x8*)&As[(wm + mi * 16 + fr) * 32 + fk];
        #pragma unroll
        for (int ni = 0; ni < 4; ++ni)
            bfr[ni] = *(const bf16x8*)&Bs[(wn + ni * 16 + fr) * 32 + fk];
        #pragma unroll
        for (int mi = 0; mi < 4; ++mi)
            #pragma unroll
            for (int ni = 0; ni < 4; ++ni) {
                if (SWAP)
                    acc[mi][ni] = __builtin_amdgcn_mfma_f32_16x16x32_bf16(
                        bfr[ni], af[mi], acc[mi][ni], 0, 0, 0);
                else
                    acc[mi][ni] = __builtin_amdgcn_mfma_f32_16x16x32_bf16(
                        af[mi], bfr[ni], acc[mi][ni], 0, 0, 0);
            }
        __syncthreads();
    }

    const int col = lane & 15, rb = (lane >> 4) * 4;

    if (MODE == 0 && SWAP) {
        const int part = n0 >> 10;
        #pragma unroll
        for (int mi = 0; mi < 4; ++mi) {
            const int m = m0 + wm + mi * 16 + col;
            if (m < NROWS) {
                const int bb = m / NTOK, n = m - bb * NTOK;
                #pragma unroll
                for (int ni = 0; ni < 4; ++ni) {
                    const int rem = (n0 & 1023) + wn + ni * 16 + rb;
                    const int hg = rem >> 6, d = rem & 63;
                    ushort4 pk;
                    pk.x = f2bf(acc[mi][ni][0]);
                    pk.y = f2bf(acc[mi][ni][1]);
                    pk.z = f2bf(acc[mi][ni][2]);
                    pk.w = f2bf(acc[mi][ni][3]);
                    *(ushort4*)(QKV + (long)part * QKV_ELEMS +
                        ((long)(bb * 16 + hg) * NTOK + n) * 64 + d) = pk;
                }
            }
        }
    } else if (MODE == 0) {
        #pragma unroll
        for (int ni = 0; ni < 4; ++ni) {
            const int o = n0 + wn + ni * 16 + col;
            const int rem = o & 1023;
            const int hg = rem >> 6, d = rem & 63;
            #pragma unroll
            for (int mi = 0; mi < 4; ++mi) {
                const int mb = m0 + wm + mi * 16 + rb;
                if (mb < NROWS) {
                    const int bb = mb / NTOK, n = mb - bb * NTOK;
                    ushort4 pk;
                    pk.x = f2bf(acc[mi][ni][0]);
                    pk.y = f2bf(acc[mi][ni][1]);
                    pk.z = f2bf(acc[mi][ni][2]);
                    pk.w = f2bf(acc[mi][ni][3]);
                    *(ushort4*)(QKV + 2L * QKV_ELEMS +
                        ((long)((bb * 16 + hg) * 64 + d)) * NTOK + n) = pk;
                }
            }
        }
    } else {
        #pragma unroll
        for (int mi = 0; mi < 4; ++mi) {
            const int m = m0 + wm + mi * 16 + col;
            if (m < NROWS) {
                #pragma unroll
                for (int ni = 0; ni < 4; ++ni) {
                    const int o = n0 + wn + ni * 16 + rb;
                    float4 pk;
                    pk.x = acc[mi][ni][0];
                    pk.y = acc[mi][ni][1];
                    pk.z = acc[mi][ni][2];
                    pk.w = acc[mi][ni][3];
                    *(float4*)(Out + (long)m * DIMC + o) = pk;
                }
            }
        }
    }
}

// ---------------------------------------------------------------------------
// RMSNorm + RoPE, one THREAD per head-token vector (round-10 version).
// ---------------------------------------------------------------------------
__global__ __launch_bounds__(256) void rope_kernel(
    ushort_t* __restrict__ Qb, ushort_t* __restrict__ Kb,
    const float* __restrict__ cosb, const float* __restrict__ sinb,
    const float* __restrict__ wq, const float* __restrict__ wk)
{
    __shared__ float wsh[64];
    const int idx = blockIdx.x * 256 + threadIdx.x;
    const int tensor = (idx >= 132096) ? 1 : 0;
    const int r = idx - tensor * 132096;
    const int n = r % NTOK;
    if (threadIdx.x < 64) wsh[threadIdx.x] = (tensor ? wk : wq)[threadIdx.x];
    __syncthreads();

    ushort_t* base = (tensor ? Kb : Qb) + (long)r * 64;
    bf16x8 xc[8];
    #pragma unroll
    for (int c = 0; c < 8; ++c) xc[c] = *(const bf16x8*)(base + c * 8);

    float ss = 0.f;
    #pragma unroll
    for (int c = 0; c < 8; ++c) {
        const f32x8 xf = __builtin_convertvector(xc[c], f32x8);
        #pragma unroll
        for (int e = 0; e < 8; ++e) ss += xf[e] * xf[e];
    }
    const float rms = rsqrtf(ss * (1.0f / 64.0f) + 1e-6f);

    const float* cosp = cosb + n * 64;
    const float* sinp = sinb + n * 64;
    #pragma unroll
    for (int c = 0; c < 8; ++c) {
        const f32x8 xf = __builtin_convertvector(xc[c], f32x8);
        const f32x8 pf = __builtin_convertvector(xc[c ^ 4], f32x8);
        const float sgn = (c < 4) ? -1.f : 1.f;
        bf16x8 o8;
        #pragma unroll
        for (int e = 0; e < 8; ++e) {
            const float xn  = xf[e] * rms * wsh[c * 8 + e];
            const float rot = sgn * pf[e] * rms * wsh[(c ^ 4) * 8 + e];
            o8[e] = (__bf16)(xn * cosp[c * 8 + e] + rot * sinp[c * 8 + e]);
        }
        *(bf16x8*)(base + c * 8) = o8;
    }
}

// ---------------------------------------------------------------------------
// Merged attention v2.
//  - Blocks [0,128): SPECIAL (first -> co-resident with patches, no tail).
//  - Blocks [128,4224): PATCH, bh = (blk-128)&127 (XCD-local per bh).
//  - Row sums via ones-MFMA fused in PV (no shuffles / LDS atomics / l_s);
//    l lands in the same lane/reg as its O element.
//  - V fragments prefetched into registers before K staging (latency hidden
//    under K-stage + S-MFMA + exp phases).
// ---------------------------------------------------------------------------
__global__ __launch_bounds__(256) void attn_kernel(
    const ushort_t* __restrict__ Qb, const ushort_t* __restrict__ Kb,
    const ushort_t* __restrict__ Vt, ushort_t* __restrict__ AO)
{
    __shared__ __align__(16) ushort_t KP_s[256 * 72];  // K (stride 72) then P (stride 280)

    const int tid = threadIdx.x;
    const int wave = tid >> 6, lane = tid & 63;
    const int m_ = lane & 15, quad = lane >> 4;
    const int nb = wave * 64;
    const int d0 = wave * 16;

    bf16x8 ones;
    #pragma unroll
    for (int e = 0; e < 8; ++e) ones[e] = (__bf16)1.0f;

    if (blockIdx.x >= 128) {
        // ================= PATCH =================
        const int blk = blockIdx.x - 128;
        const int bh = blk & 127, qr = blk >> 7;
        const int b = bh >> 4, h = bh & 15;

        int r0 = qr - 3; if (r0 < 0) r0 = 0;
        int r1 = qr + 3; if (r1 > 31) r1 = 31;
        const int limit = 8 + (r1 - r0 + 1) * 32;

        const ushort_t* Qg  = Qb + ((long)bh * NTOK + 8 + qr * 32) * 64;
        const ushort_t* Kg  = Kb + (long)bh * NTOK * 64;
        const ushort_t* Vtg = Vt + (long)bh * 64 * NTOK;

        // Q fragments direct from global
        bf16x8 af[2][2];
        #pragma unroll
        for (int mt = 0; mt < 2; ++mt)
            #pragma unroll
            for (int ks = 0; ks < 2; ++ks)
                af[mt][ks] = *(const bf16x8*)(Qg + (mt * 16 + m_) * 64 + ks * 32 + quad * 8);

        // V fragments prefetched (addresses independent of S results)
        bf16x8 bv[8];
        #pragma unroll
        for (int ks = 0; ks < 8; ++ks) {
            const int slot0 = ks * 32 + quad * 8;
            int tok0;
            if (slot0 >= limit) tok0 = 0;          // P there is 0
            else if (slot0 < 8) tok0 = slot0;
            else tok0 = 8 + r0 * 32 + (slot0 - 8);
            bv[ks] = *(const bf16x8*)(Vtg + (long)(d0 + m_) * NTOK + tok0);
        }

        for (int c = tid; c < limit * 8; c += 256) {
            const int slot = c >> 3, c8 = (c & 7) * 8;
            const int tok = slot + (slot >= 8 ? r0 * 32 : 0);
            *(bf16x8*)&KP_s[slot * 72 + c8] = *(const bf16x8*)(Kg + (long)tok * 64 + c8);
        }
        __syncthreads();

        bf16x8 bfr[4][2];
        #pragma unroll
        for (int nt = 0; nt < 4; ++nt)
            #pragma unroll
            for (int ks = 0; ks < 2; ++ks)
                bfr[nt][ks] = *(const bf16x8*)&KP_s[(nb + nt * 16 + m_) * 72 + ks * 32 + quad * 8];

        f32x4 sacc[2][4] = {};
        #pragma unroll
        for (int mt = 0; mt < 2; ++mt)
            #pragma unroll
            for (int nt = 0; nt < 4; ++nt) {
                sacc[mt][nt] = __builtin_amdgcn_mfma_f32_16x16x32_bf16(
                    af[mt][0], bfr[nt][0], sacc[mt][nt], 0, 0, 0);
                sacc[mt][nt] = __builtin_amdgcn_mfma_f32_16x16x32_bf16(
                    af[mt][1], bfr[nt][1], sacc[mt][nt], 0, 0, 0);
            }
        __syncthreads();   // K fragment reads done -> safe to overwrite with P

        #pragma unroll
        for (int mt = 0; mt < 2; ++mt)
            #pragma unroll
            for (int nt = 0; nt < 4; ++nt) {
                const int slot = nb + nt * 16 + m_;
                const int kc = (slot - 8) & 31;
                #pragma unroll
                for (int reg = 0; reg < 4; ++reg) {
                    const int qm = mt * 16 + quad * 4 + reg;
                    const bool val = (slot < 8) ||
                        ((slot < limit) && ((unsigned)(kc - qm + 3) <= 6u));
                    const float p = val ? __expf(sacc[mt][nt][reg] * 0.125f) : 0.f;
                    KP_s[qm * 280 + slot] = f2bf(p);
                }
            }
        __syncthreads();

        f32x4 oacc[2] = {}, lacc[2] = {};
        #pragma unroll
        for (int ks = 0; ks < 8; ++ks) {
            #pragma unroll
            for (int mt = 0; mt < 2; ++mt) {
                const bf16x8 ap = *(const bf16x8*)&KP_s[(mt * 16 + m_) * 280 + ks * 32 + quad * 8];
                oacc[mt] = __builtin_amdgcn_mfma_f32_16x16x32_bf16(ap, bv[ks], oacc[mt], 0, 0, 0);
                lacc[mt] = __builtin_amdgcn_mfma_f32_16x16x32_bf16(ap, ones,   lacc[mt], 0, 0, 0);
            }
        }
        #pragma unroll
        for (int mt = 0; mt < 2; ++mt)
            #pragma unroll
            for (int reg = 0; reg < 4; ++reg) {
                const int qm = mt * 16 + quad * 4 + reg;
                const int tok = 8 + qr * 32 + qm;
                AO[((long)(b * NTOK + tok)) * DIMC + h * 64 + d0 + m_] =
                    f2bf(oacc[mt][reg] / lacc[mt][reg]);
            }
    } else {
        // ================= SPECIAL =================
        const int bh = blockIdx.x;
        const int b = bh >> 4, h = bh & 15;
        const ushort_t* Kg  = Kb + (long)bh * NTOK * 64;
        const ushort_t* Vtg = Vt + (long)bh * 64 * NTOK;

        // Q fragments direct (rows >= 8 zero -> their P=1 rows are discarded)
        bf16x8 afs[2];
        if (m_ < 8) {
            #pragma unroll
            for (int ks = 0; ks < 2; ++ks)
                afs[ks] = *(const bf16x8*)(Qb + ((long)bh * NTOK + m_) * 64 + ks * 32 + quad * 8);
        } else {
            #pragma unroll
            for (int ks = 0; ks < 2; ++ks)
                #pragma unroll
                for (int e = 0; e < 8; ++e) afs[ks][e] = (__bf16)0.f;
        }

        f32x4 oacc = {}, lacc = {};
        for (int ch = 0; ch < 5; ++ch) {
            const int tok0 = ch * 256;
            const int limit = (NTOK - tok0 < 256) ? (NTOK - tok0) : 256;

            // prefetch this chunk's V fragments
            bf16x8 bv[8];
            #pragma unroll
            for (int ks = 0; ks < 8; ++ks) {
                const int slot0 = ks * 32 + quad * 8;
                const int tok = tok0 + ((slot0 < limit) ? slot0 : 0);
                bv[ks] = *(const bf16x8*)(Vtg + (long)(d0 + m_) * NTOK + tok);
            }

            __syncthreads();   // prior PV's P reads complete before K restage
            for (int c = tid; c < limit * 8; c += 256) {
                const int slot = c >> 3, c8 = (c & 7) * 8;
                *(bf16x8*)&KP_s[slot * 72 + c8] =
                    *(const bf16x8*)(Kg + (long)(tok0 + slot) * 64 + c8);
            }
            __syncthreads();

            bf16x8 bfr[4][2];
            #pragma unroll
            for (int nt = 0; nt < 4; ++nt)
                #pragma unroll
                for (int ks = 0; ks < 2; ++ks)
                    bfr[nt][ks] = *(const bf16x8*)&KP_s[(nb + nt * 16 + m_) * 72 + ks * 32 + quad * 8];
            f32x4 sacc[4] = {};
            #pragma unroll
            for (int nt = 0; nt < 4; ++nt) {
                sacc[nt] = __builtin_amdgcn_mfma_f32_16x16x32_bf16(afs[0], bfr[nt][0], sacc[nt], 0, 0, 0);
                sacc[nt] = __builtin_amdgcn_mfma_f32_16x16x32_bf16(afs[1], bfr[nt][1], sacc[nt], 0, 0, 0);
            }
            __syncthreads();   // K fragment reads done -> overlay P

            #pragma unroll
            for (int nt = 0; nt < 4; ++nt) {
                const int slot = nb + nt * 16 + m_;
                const bool val = (slot < limit);
                #pragma unroll
                for (int reg = 0; reg < 4; ++reg) {
                    const int qm = quad * 4 + reg;
                    const float p = val ? __expf(sacc[nt][reg] * 0.125f) : 0.f;
                    KP_s[qm * 280 + slot] = f2bf(p);
                }
            }
            __syncthreads();

            #pragma unroll
            for (int ks = 0; ks < 8; ++ks) {
                const bf16x8 ap = *(const bf16x8*)&KP_s[m_ * 280 + ks * 32 + quad * 8];
                oacc = __builtin_amdgcn_mfma_f32_16x16x32_bf16(ap, bv[ks], oacc, 0, 0, 0);
                lacc = __builtin_amdgcn_mfma_f32_16x16x32_bf16(ap, ones,   lacc, 0, 0, 0);
            }
        }

        #pragma unroll
        for (int reg = 0; reg < 4; ++reg) {
            const int qm = quad * 4 + reg;
            if (qm < 8) {
                AO[((long)(b * NTOK + qm)) * DIMC + h * 64 + d0 + m_] =
                    f2bf(oacc[reg] / lacc[reg]);
            }
        }
    }
}

extern "C" void kernel_launch(void* const* d_in, const int* in_sizes, int n_in,
                              void* d_out, int out_size, void* d_ws, size_t ws_size,
                              hipStream_t stream) {
    const float* X    = (const float*)d_in[0];
    const float* fc   = (const float*)d_in[1];
    const float* fs   = (const float*)d_in[2];
    const float* qkvw = (const float*)d_in[3];
    const float* outw = (const float*)d_in[4];
    const float* nqw  = (const float*)d_in[5];
    const float* nkw  = (const float*)d_in[6];

    ushort_t* Qb  = (ushort_t*)d_ws;     // 16.9 MB each
    ushort_t* Kb  = Qb + QKV_ELEMS;
    ushort_t* Vt  = Kb + QKV_ELEMS;      // dim-major [bh][d][n]
    ushort_t* AO  = Vt + QKV_ELEMS;
    ushort_t* Xb  = AO + QKV_ELEMS;      // bf16 X (16.9 MB)
    ushort_t* Wqb = Xb + XE;             // bf16 qkv_w (6.3 MB)
    ushort_t* Wob = Wqb + QWE;           // bf16 out_w (2.1 MB)
    float* Out = (float*)d_out;

    cvt_kernel<<<6176, 256, 0, stream>>>(X, qkvw, outw, Xb, Wqb, Wob);
    gemm_kernel<0, true><<<dim3(16, 65), 256, 0, stream>>>(Xb, Wqb, Qb, nullptr, 0);
    gemm_kernel<0, false><<<dim3(8, 65), 256, 0, stream>>>(Xb, Wqb, Qb, nullptr, 2048);
    rope_kernel<<<1032, 256, 0, stream>>>(Qb, Kb, fc, fs, nqw, nkw);
    attn_kernel<<<4224, 256, 0, stream>>>(Qb, Kb, Vt, AO);
    gemm_kernel<1, true><<<dim3(8, 65), 256, 0, stream>>>(AO, Wob, nullptr, Out, 0);
}

// Round 12
// 311.685 us; speedup vs baseline: 1.2510x; 1.0259x over previous
//
#include <hip/hip_runtime.h>
#include <hip/hip_bf16.h>

typedef unsigned short ushort_t;
typedef __bf16 bf16x8 __attribute__((ext_vector_type(8)));
typedef float f32x4 __attribute__((ext_vector_type(4)));
typedef float f32x8 __attribute__((ext_vector_type(8)));

#define NTOK 1032
#define NROWS 8256       // B*N = 8*1032
#define DIMC 1024
#define QKV_ELEMS 8454144  // 8*16*1032*64 elements per tensor
#define XE 8454144         // X elements (8256*1024)
#define QWE 3145728        // qkv_w elements (3072*1024)
#define OWE 1048576        // out_w elements (1024*1024)

__device__ __forceinline__ float bf2f(ushort_t u) {
    union { unsigned int i; float f; } v; v.i = ((unsigned int)u) << 16; return v.f;
}
__device__ __forceinline__ ushort_t f2bf(float f) {
    union { float f; unsigned int i; } v; v.f = f;
    unsigned int r = v.i + 0x7fffu + ((v.i >> 16) & 1u);
    return (ushort_t)(r >> 16);
}
__device__ __forceinline__ bf16x8 cvt8(const float* p) {
    const float4 a = *(const float4*)p;
    const float4 b = *(const float4*)(p + 4);
    bf16x8 r;
    r[0] = (__bf16)a.x; r[1] = (__bf16)a.y; r[2] = (__bf16)a.z; r[3] = (__bf16)a.w;
    r[4] = (__bf16)b.x; r[5] = (__bf16)b.y; r[6] = (__bf16)b.z; r[7] = (__bf16)b.w;
    return r;
}
__device__ __forceinline__ void load_lds16(const ushort_t* g, ushort_t* l) {
    __builtin_amdgcn_global_load_lds(
        (const __attribute__((address_space(1))) unsigned int*)g,
        (__attribute__((address_space(3))) unsigned int*)l, 16, 0, 0);
}

// ---------------------------------------------------------------------------
// fp32 -> bf16 pre-conversion of X, qkv_w, out_w (RNE).
// ---------------------------------------------------------------------------
__global__ __launch_bounds__(256) void cvt_kernel(
    const float* __restrict__ X, const float* __restrict__ Wq,
    const float* __restrict__ Wo,
    ushort_t* __restrict__ Xb, ushort_t* __restrict__ Wqb,
    ushort_t* __restrict__ Wob)
{
    const long i8 = ((long)blockIdx.x * 256 + threadIdx.x) * 8;
    const float* src;
    ushort_t* dst;
    long off;
    if (i8 < XE)            { src = X;  dst = Xb;  off = i8; }
    else if (i8 < XE + QWE) { src = Wq; dst = Wqb; off = i8 - XE; }
    else                    { src = Wo; dst = Wob; off = i8 - XE - QWE; }
    *(bf16x8*)(dst + off) = cvt8(src + off);
}

// ---------------------------------------------------------------------------
// GEMM, BK=64 K-loop: 4 LDS buffers (stride-32 each -> 2-way bank aliasing,
// wave-contiguous global_load_lds), 16 iterations (half the barrier drains
// of BK=32). Accumulation order identical to BK=32 (ks0 then ks1 chained).
// MODE 0: QKV projection, runtime part branch:
//   blocks x<16 (Q,K): swapped mfma -> regs contiguous in d -> 8B stores
//   blocks x>=16 (V):  unswapped   -> regs contiguous in n -> 8B Vt stores
// MODE 1: out proj, swapped -> float4 stores.
// ---------------------------------------------------------------------------
template<int MODE>
__global__ __launch_bounds__(256) void gemm_kernel(
    const ushort_t* __restrict__ A, const ushort_t* __restrict__ W,
    ushort_t* __restrict__ QKV, float* __restrict__ Out)
{
    __shared__ __align__(16) ushort_t As0[128 * 32];
    __shared__ __align__(16) ushort_t As1[128 * 32];
    __shared__ __align__(16) ushort_t Bs0[128 * 32];
    __shared__ __align__(16) ushort_t Bs1[128 * 32];
    const int tid  = threadIdx.x;
    const int wave = tid >> 6, lane = tid & 63;
    const int m0 = blockIdx.y * 128;
    const int n0 = blockIdx.x * 128;
    const bool swap = (MODE == 1) || (blockIdx.x < 16);

    f32x4 acc[4][4] = {};

    const int s0 = tid, s1 = tid + 256;      // slots: row = s>>2, chunk = s&3
    int ar0 = m0 + (s0 >> 2); if (ar0 > NROWS - 1) ar0 = NROWS - 1;
    int ar1 = m0 + (s1 >> 2); if (ar1 > NROWS - 1) ar1 = NROWS - 1;
    const int br0 = n0 + (s0 >> 2);
    const int br1 = n0 + (s1 >> 2);
    const int kc0 = (s0 & 3) * 8, kc1 = (s1 & 3) * 8;

    const ushort_t* ga0 = A + (long)ar0 * DIMC + kc0;
    const ushort_t* ga1 = A + (long)ar1 * DIMC + kc1;
    const ushort_t* gw0 = W + (long)br0 * DIMC + kc0;
    const ushort_t* gw1 = W + (long)br1 * DIMC + kc1;
    ushort_t* la00 = &As0[s0 * 8]; ushort_t* la01 = &As1[s0 * 8];
    ushort_t* la10 = &As0[s1 * 8]; ushort_t* la11 = &As1[s1 * 8];
    ushort_t* lb00 = &Bs0[s0 * 8]; ushort_t* lb01 = &Bs1[s0 * 8];
    ushort_t* lb10 = &Bs0[s1 * 8]; ushort_t* lb11 = &Bs1[s1 * 8];

    const int wm = (wave >> 1) * 64, wn = (wave & 1) * 64;
    const int fr = lane & 15, fk = (lane >> 4) * 8;

    for (int k0 = 0; k0 < DIMC; k0 += 64) {
        load_lds16(ga0 + k0,      la00);
        load_lds16(ga0 + k0 + 32, la01);
        load_lds16(ga1 + k0,      la10);
        load_lds16(ga1 + k0 + 32, la11);
        load_lds16(gw0 + k0,      lb00);
        load_lds16(gw0 + k0 + 32, lb01);
        load_lds16(gw1 + k0,      lb10);
        load_lds16(gw1 + k0 + 32, lb11);
        __syncthreads();

        bf16x8 af[4][2], bfr[4][2];
        #pragma unroll
        for (int mi = 0; mi < 4; ++mi) {
            af[mi][0] = *(const bf16x8*)&As0[(wm + mi * 16 + fr) * 32 + fk];
            af[mi][1] = *(const bf16x8*)&As1[(wm + mi * 16 + fr) * 32 + fk];
        }
        #pragma unroll
        for (int ni = 0; ni < 4; ++ni) {
            bfr[ni][0] = *(const bf16x8*)&Bs0[(wn + ni * 16 + fr) * 32 + fk];
            bfr[ni][1] = *(const bf16x8*)&Bs1[(wn + ni * 16 + fr) * 32 + fk];
        }
        if (swap) {
            #pragma unroll
            for (int mi = 0; mi < 4; ++mi)
                #pragma unroll
                for (int ni = 0; ni < 4; ++ni) {
                    acc[mi][ni] = __builtin_amdgcn_mfma_f32_16x16x32_bf16(
                        bfr[ni][0], af[mi][0], acc[mi][ni], 0, 0, 0);
                    acc[mi][ni] = __builtin_amdgcn_mfma_f32_16x16x32_bf16(
                        bfr[ni][1], af[mi][1], acc[mi][ni], 0, 0, 0);
                }
        } else {
            #pragma unroll
            for (int mi = 0; mi < 4; ++mi)
                #pragma unroll
                for (int ni = 0; ni < 4; ++ni) {
                    acc[mi][ni] = __builtin_amdgcn_mfma_f32_16x16x32_bf16(
                        af[mi][0], bfr[ni][0], acc[mi][ni], 0, 0, 0);
                    acc[mi][ni] = __builtin_amdgcn_mfma_f32_16x16x32_bf16(
                        af[mi][1], bfr[ni][1], acc[mi][ni], 0, 0, 0);
                }
        }
        __syncthreads();
    }

    const int col = lane & 15, rb = (lane >> 4) * 4;

    if (MODE == 0 && swap) {
        // Q/K: D[o][m] -> col=m, regs contiguous in o (=d)
        const int part = n0 >> 10;
        #pragma unroll
        for (int mi = 0; mi < 4; ++mi) {
            const int m = m0 + wm + mi * 16 + col;
            if (m < NROWS) {
                const int bb = m / NTOK, n = m - bb * NTOK;
                #pragma unroll
                for (int ni = 0; ni < 4; ++ni) {
                    const int rem = (n0 & 1023) + wn + ni * 16 + rb;
                    const int hg = rem >> 6, d = rem & 63;
                    ushort4 pk;
                    pk.x = f2bf(acc[mi][ni][0]);
                    pk.y = f2bf(acc[mi][ni][1]);
                    pk.z = f2bf(acc[mi][ni][2]);
                    pk.w = f2bf(acc[mi][ni][3]);
                    *(ushort4*)(QKV + (long)part * QKV_ELEMS +
                        ((long)(bb * 16 + hg) * NTOK + n) * 64 + d) = pk;
                }
            }
        }
    } else if (MODE == 0) {
        // V: D[m][o] -> regs contiguous in m (=n), store to Vt[bh][d][n]
        #pragma unroll
        for (int ni = 0; ni < 4; ++ni) {
            const int o = n0 + wn + ni * 16 + col;
            const int rem = o & 1023;
            const int hg = rem >> 6, d = rem & 63;
            #pragma unroll
            for (int mi = 0; mi < 4; ++mi) {
                const int mb = m0 + wm + mi * 16 + rb;
                if (mb < NROWS) {
                    const int bb = mb / NTOK, n = mb - bb * NTOK;
                    ushort4 pk;
                    pk.x = f2bf(acc[mi][ni][0]);
                    pk.y = f2bf(acc[mi][ni][1]);
                    pk.z = f2bf(acc[mi][ni][2]);
                    pk.w = f2bf(acc[mi][ni][3]);
                    *(ushort4*)(QKV + 2L * QKV_ELEMS +
                        ((long)((bb * 16 + hg) * 64 + d)) * NTOK + n) = pk;
                }
            }
        }
    } else {
        // out proj: col=m, regs contiguous in o -> float4 stores
        #pragma unroll
        for (int mi = 0; mi < 4; ++mi) {
            const int m = m0 + wm + mi * 16 + col;
            if (m < NROWS) {
                #pragma unroll
                for (int ni = 0; ni < 4; ++ni) {
                    const int o = n0 + wn + ni * 16 + rb;
                    float4 pk;
                    pk.x = acc[mi][ni][0];
                    pk.y = acc[mi][ni][1];
                    pk.z = acc[mi][ni][2];
                    pk.w = acc[mi][ni][3];
                    *(float4*)(Out + (long)m * DIMC + o) = pk;
                }
            }
        }
    }
}

// ---------------------------------------------------------------------------
// RMSNorm + RoPE, one THREAD per head-token vector (round-10 version).
// ---------------------------------------------------------------------------
__global__ __launch_bounds__(256) void rope_kernel(
    ushort_t* __restrict__ Qb, ushort_t* __restrict__ Kb,
    const float* __restrict__ cosb, const float* __restrict__ sinb,
    const float* __restrict__ wq, const float* __restrict__ wk)
{
    __shared__ float wsh[64];
    const int idx = blockIdx.x * 256 + threadIdx.x;
    const int tensor = (idx >= 132096) ? 1 : 0;
    const int r = idx - tensor * 132096;
    const int n = r % NTOK;
    if (threadIdx.x < 64) wsh[threadIdx.x] = (tensor ? wk : wq)[threadIdx.x];
    __syncthreads();

    ushort_t* base = (tensor ? Kb : Qb) + (long)r * 64;
    bf16x8 xc[8];
    #pragma unroll
    for (int c = 0; c < 8; ++c) xc[c] = *(const bf16x8*)(base + c * 8);

    float ss = 0.f;
    #pragma unroll
    for (int c = 0; c < 8; ++c) {
        const f32x8 xf = __builtin_convertvector(xc[c], f32x8);
        #pragma unroll
        for (int e = 0; e < 8; ++e) ss += xf[e] * xf[e];
    }
    const float rms = rsqrtf(ss * (1.0f / 64.0f) + 1e-6f);

    const float* cosp = cosb + n * 64;
    const float* sinp = sinb + n * 64;
    #pragma unroll
    for (int c = 0; c < 8; ++c) {
        const f32x8 xf = __builtin_convertvector(xc[c], f32x8);
        const f32x8 pf = __builtin_convertvector(xc[c ^ 4], f32x8);
        const float sgn = (c < 4) ? -1.f : 1.f;
        bf16x8 o8;
        #pragma unroll
        for (int e = 0; e < 8; ++e) {
            const float xn  = xf[e] * rms * wsh[c * 8 + e];
            const float rot = sgn * pf[e] * rms * wsh[(c ^ 4) * 8 + e];
            o8[e] = (__bf16)(xn * cosp[c * 8 + e] + rot * sinp[c * 8 + e]);
        }
        *(bf16x8*)(base + c * 8) = o8;
    }
}

// ---------------------------------------------------------------------------
// Merged attention (round-11 version: specials first, ones-MFMA row sums,
// V register prefetch, XCD-local bh mapping).
// ---------------------------------------------------------------------------
__global__ __launch_bounds__(256) void attn_kernel(
    const ushort_t* __restrict__ Qb, const ushort_t* __restrict__ Kb,
    const ushort_t* __restrict__ Vt, ushort_t* __restrict__ AO)
{
    __shared__ __align__(16) ushort_t KP_s[256 * 72];

    const int tid = threadIdx.x;
    const int wave = tid >> 6, lane = tid & 63;
    const int m_ = lane & 15, quad = lane >> 4;
    const int nb = wave * 64;
    const int d0 = wave * 16;

    bf16x8 ones;
    #pragma unroll
    for (int e = 0; e < 8; ++e) ones[e] = (__bf16)1.0f;

    if (blockIdx.x >= 128) {
        // ================= PATCH =================
        const int blk = blockIdx.x - 128;
        const int bh = blk & 127, qr = blk >> 7;
        const int b = bh >> 4, h = bh & 15;

        int r0 = qr - 3; if (r0 < 0) r0 = 0;
        int r1 = qr + 3; if (r1 > 31) r1 = 31;
        const int limit = 8 + (r1 - r0 + 1) * 32;

        const ushort_t* Qg  = Qb + ((long)bh * NTOK + 8 + qr * 32) * 64;
        const ushort_t* Kg  = Kb + (long)bh * NTOK * 64;
        const ushort_t* Vtg = Vt + (long)bh * 64 * NTOK;

        bf16x8 af[2][2];
        #pragma unroll
        for (int mt = 0; mt < 2; ++mt)
            #pragma unroll
            for (int ks = 0; ks < 2; ++ks)
                af[mt][ks] = *(const bf16x8*)(Qg + (mt * 16 + m_) * 64 + ks * 32 + quad * 8);

        bf16x8 bv[8];
        #pragma unroll
        for (int ks = 0; ks < 8; ++ks) {
            const int slot0 = ks * 32 + quad * 8;
            int tok0;
            if (slot0 >= limit) tok0 = 0;
            else if (slot0 < 8) tok0 = slot0;
            else tok0 = 8 + r0 * 32 + (slot0 - 8);
            bv[ks] = *(const bf16x8*)(Vtg + (long)(d0 + m_) * NTOK + tok0);
        }

        for (int c = tid; c < limit * 8; c += 256) {
            const int slot = c >> 3, c8 = (c & 7) * 8;
            const int tok = slot + (slot >= 8 ? r0 * 32 : 0);
            *(bf16x8*)&KP_s[slot * 72 + c8] = *(const bf16x8*)(Kg + (long)tok * 64 + c8);
        }
        __syncthreads();

        bf16x8 bfr[4][2];
        #pragma unroll
        for (int nt = 0; nt < 4; ++nt)
            #pragma unroll
            for (int ks = 0; ks < 2; ++ks)
                bfr[nt][ks] = *(const bf16x8*)&KP_s[(nb + nt * 16 + m_) * 72 + ks * 32 + quad * 8];

        f32x4 sacc[2][4] = {};
        #pragma unroll
        for (int mt = 0; mt < 2; ++mt)
            #pragma unroll
            for (int nt = 0; nt < 4; ++nt) {
                sacc[mt][nt] = __builtin_amdgcn_mfma_f32_16x16x32_bf16(
                    af[mt][0], bfr[nt][0], sacc[mt][nt], 0, 0, 0);
                sacc[mt][nt] = __builtin_amdgcn_mfma_f32_16x16x32_bf16(
                    af[mt][1], bfr[nt][1], sacc[mt][nt], 0, 0, 0);
            }
        __syncthreads();

        #pragma unroll
        for (int mt = 0; mt < 2; ++mt)
            #pragma unroll
            for (int nt = 0; nt < 4; ++nt) {
                const int slot = nb + nt * 16 + m_;
                const int kc = (slot - 8) & 31;
                #pragma unroll
                for (int reg = 0; reg < 4; ++reg) {
                    const int qm = mt * 16 + quad * 4 + reg;
                    const bool val = (slot < 8) ||
                        ((slot < limit) && ((unsigned)(kc - qm + 3) <= 6u));
                    const float p = val ? __expf(sacc[mt][nt][reg] * 0.125f) : 0.f;
                    KP_s[qm * 280 + slot] = f2bf(p);
                }
            }
        __syncthreads();

        f32x4 oacc[2] = {}, lacc[2] = {};
        #pragma unroll
        for (int ks = 0; ks < 8; ++ks) {
            #pragma unroll
            for (int mt = 0; mt < 2; ++mt) {
                const bf16x8 ap = *(const bf16x8*)&KP_s[(mt * 16 + m_) * 280 + ks * 32 + quad * 8];
                oacc[mt] = __builtin_amdgcn_mfma_f32_16x16x32_bf16(ap, bv[ks], oacc[mt], 0, 0, 0);
                lacc[mt] = __builtin_amdgcn_mfma_f32_16x16x32_bf16(ap, ones,   lacc[mt], 0, 0, 0);
            }
        }
        #pragma unroll
        for (int mt = 0; mt < 2; ++mt)
            #pragma unroll
            for (int reg = 0; reg < 4; ++reg) {
                const int qm = mt * 16 + quad * 4 + reg;
                const int tok = 8 + qr * 32 + qm;
                AO[((long)(b * NTOK + tok)) * DIMC + h * 64 + d0 + m_] =
                    f2bf(oacc[mt][reg] / lacc[mt][reg]);
            }
    } else {
        // ================= SPECIAL =================
        const int bh = blockIdx.x;
        const int b = bh >> 4, h = bh & 15;
        const ushort_t* Kg  = Kb + (long)bh * NTOK * 64;
        const ushort_t* Vtg = Vt + (long)bh * 64 * NTOK;

        bf16x8 afs[2];
        if (m_ < 8) {
            #pragma unroll
            for (int ks = 0; ks < 2; ++ks)
                afs[ks] = *(const bf16x8*)(Qb + ((long)bh * NTOK + m_) * 64 + ks * 32 + quad * 8);
        } else {
            #pragma unroll
            for (int ks = 0; ks < 2; ++ks)
                #pragma unroll
                for (int e = 0; e < 8; ++e) afs[ks][e] = (__bf16)0.f;
        }

        f32x4 oacc = {}, lacc = {};
        for (int ch = 0; ch < 5; ++ch) {
            const int tok0 = ch * 256;
            const int limit = (NTOK - tok0 < 256) ? (NTOK - tok0) : 256;

            bf16x8 bv[8];
            #pragma unroll
            for (int ks = 0; ks < 8; ++ks) {
                const int slot0 = ks * 32 + quad * 8;
                const int tok = tok0 + ((slot0 < limit) ? slot0 : 0);
                bv[ks] = *(const bf16x8*)(Vtg + (long)(d0 + m_) * NTOK + tok);
            }

            __syncthreads();
            for (int c = tid; c < limit * 8; c += 256) {
                const int slot = c >> 3, c8 = (c & 7) * 8;
                *(bf16x8*)&KP_s[slot * 72 + c8] =
                    *(const bf16x8*)(Kg + (long)(tok0 + slot) * 64 + c8);
            }
            __syncthreads();

            bf16x8 bfr[4][2];
            #pragma unroll
            for (int nt = 0; nt < 4; ++nt)
                #pragma unroll
                for (int ks = 0; ks < 2; ++ks)
                    bfr[nt][ks] = *(const bf16x8*)&KP_s[(nb + nt * 16 + m_) * 72 + ks * 32 + quad * 8];
            f32x4 sacc[4] = {};
            #pragma unroll
            for (int nt = 0; nt < 4; ++nt) {
                sacc[nt] = __builtin_amdgcn_mfma_f32_16x16x32_bf16(afs[0], bfr[nt][0], sacc[nt], 0, 0, 0);
                sacc[nt] = __builtin_amdgcn_mfma_f32_16x16x32_bf16(afs[1], bfr[nt][1], sacc[nt], 0, 0, 0);
            }
            __syncthreads();

            #pragma unroll
            for (int nt = 0; nt < 4; ++nt) {
                const int slot = nb + nt * 16 + m_;
                const bool val = (slot < limit);
                #pragma unroll
                for (int reg = 0; reg < 4; ++reg) {
                    const int qm = quad * 4 + reg;
                    const float p = val ? __expf(sacc[nt][reg] * 0.125f) : 0.f;
                    KP_s[qm * 280 + slot] = f2bf(p);
                }
            }
            __syncthreads();

            #pragma unroll
            for (int ks = 0; ks < 8; ++ks) {
                const bf16x8 ap = *(const bf16x8*)&KP_s[m_ * 280 + ks * 32 + quad * 8];
                oacc = __builtin_amdgcn_mfma_f32_16x16x32_bf16(ap, bv[ks], oacc, 0, 0, 0);
                lacc = __builtin_amdgcn_mfma_f32_16x16x32_bf16(ap, ones,   lacc, 0, 0, 0);
            }
        }

        #pragma unroll
        for (int reg = 0; reg < 4; ++reg) {
            const int qm = quad * 4 + reg;
            if (qm < 8) {
                AO[((long)(b * NTOK + qm)) * DIMC + h * 64 + d0 + m_] =
                    f2bf(oacc[reg] / lacc[reg]);
            }
        }
    }
}

extern "C" void kernel_launch(void* const* d_in, const int* in_sizes, int n_in,
                              void* d_out, int out_size, void* d_ws, size_t ws_size,
                              hipStream_t stream) {
    const float* X    = (const float*)d_in[0];
    const float* fc   = (const float*)d_in[1];
    const float* fs   = (const float*)d_in[2];
    const float* qkvw = (const float*)d_in[3];
    const float* outw = (const float*)d_in[4];
    const float* nqw  = (const float*)d_in[5];
    const float* nkw  = (const float*)d_in[6];

    ushort_t* Qb  = (ushort_t*)d_ws;     // 16.9 MB each
    ushort_t* Kb  = Qb + QKV_ELEMS;
    ushort_t* Vt  = Kb + QKV_ELEMS;      // dim-major [bh][d][n]
    ushort_t* AO  = Vt + QKV_ELEMS;
    ushort_t* Xb  = AO + QKV_ELEMS;      // bf16 X (16.9 MB)
    ushort_t* Wqb = Xb + XE;             // bf16 qkv_w (6.3 MB)
    ushort_t* Wob = Wqb + QWE;           // bf16 out_w (2.1 MB)
    float* Out = (float*)d_out;

    cvt_kernel<<<6176, 256, 0, stream>>>(X, qkvw, outw, Xb, Wqb, Wob);
    // merged Q/K/V projection (BK=64), runtime swap per column block
    gemm_kernel<0><<<dim3(24, 65), 256, 0, stream>>>(Xb, Wqb, Qb, nullptr);
    rope_kernel<<<1032, 256, 0, stream>>>(Qb, Kb, fc, fs, nqw, nkw);
    attn_kernel<<<4224, 256, 0, stream>>>(Qb, Kb, Vt, AO);
    gemm_kernel<1><<<dim3(8, 65), 256, 0, stream>>>(AO, Wob, nullptr, Out);
}

// Round 13
// 304.044 us; speedup vs baseline: 1.2824x; 1.0251x over previous
//
#include <hip/hip_runtime.h>
#include <hip/hip_bf16.h>

typedef unsigned short ushort_t;
typedef __bf16 bf16x8 __attribute__((ext_vector_type(8)));
typedef float f32x4 __attribute__((ext_vector_type(4)));
typedef float f32x8 __attribute__((ext_vector_type(8)));

#define NTOK 1032
#define NROWS 8256       // B*N = 8*1032
#define DIMC 1024
#define QKV_ELEMS 8454144  // 8*16*1032*64 elements per tensor
#define XE 8454144         // X elements (8256*1024)
#define QWE 3145728        // qkv_w elements (3072*1024)
#define OWE 1048576        // out_w elements (1024*1024)

__device__ __forceinline__ float bf2f(ushort_t u) {
    union { unsigned int i; float f; } v; v.i = ((unsigned int)u) << 16; return v.f;
}
__device__ __forceinline__ ushort_t f2bf(float f) {
    union { float f; unsigned int i; } v; v.f = f;
    unsigned int r = v.i + 0x7fffu + ((v.i >> 16) & 1u);
    return (ushort_t)(r >> 16);
}
__device__ __forceinline__ bf16x8 cvt8(const float* p) {
    const float4 a = *(const float4*)p;
    const float4 b = *(const float4*)(p + 4);
    bf16x8 r;
    r[0] = (__bf16)a.x; r[1] = (__bf16)a.y; r[2] = (__bf16)a.z; r[3] = (__bf16)a.w;
    r[4] = (__bf16)b.x; r[5] = (__bf16)b.y; r[6] = (__bf16)b.z; r[7] = (__bf16)b.w;
    return r;
}
__device__ __forceinline__ void load_lds16(const ushort_t* g, ushort_t* l) {
    __builtin_amdgcn_global_load_lds(
        (const __attribute__((address_space(1))) unsigned int*)g,
        (__attribute__((address_space(3))) unsigned int*)l, 16, 0, 0);
}

// ---------------------------------------------------------------------------
// fp32 -> bf16 pre-conversion of X, qkv_w, out_w (RNE).
// ---------------------------------------------------------------------------
__global__ __launch_bounds__(256) void cvt_kernel(
    const float* __restrict__ X, const float* __restrict__ Wq,
    const float* __restrict__ Wo,
    ushort_t* __restrict__ Xb, ushort_t* __restrict__ Wqb,
    ushort_t* __restrict__ Wob)
{
    const long i8 = ((long)blockIdx.x * 256 + threadIdx.x) * 8;
    const float* src;
    ushort_t* dst;
    long off;
    if (i8 < XE)            { src = X;  dst = Xb;  off = i8; }
    else if (i8 < XE + QWE) { src = Wq; dst = Wqb; off = i8 - XE; }
    else                    { src = Wo; dst = Wob; off = i8 - XE - QWE; }
    *(bf16x8*)(dst + off) = cvt8(src + off);
}

// ---------------------------------------------------------------------------
// GEMM, BK=64 K-loop with SEQUENTIAL half-bodies: two BK=32-style fragment
// load + 16-MFMA groups per barrier pair. 8 live fragments (32 VGPRs) instead
// of 16 -> restores occupancy lost in round 12, keeps the halved barrier-
// drain count. Accumulation order bit-identical to BK=32 chaining.
// MODE 0: QKV projection (blocks x<16 Q/K swapped; x>=16 V unswapped -> Vt).
// MODE 1: out proj, swapped -> float4 stores.
// ---------------------------------------------------------------------------
template<int MODE>
__global__ __launch_bounds__(256) void gemm_kernel(
    const ushort_t* __restrict__ A, const ushort_t* __restrict__ W,
    ushort_t* __restrict__ QKV, float* __restrict__ Out)
{
    __shared__ __align__(16) ushort_t As0[128 * 32];
    __shared__ __align__(16) ushort_t As1[128 * 32];
    __shared__ __align__(16) ushort_t Bs0[128 * 32];
    __shared__ __align__(16) ushort_t Bs1[128 * 32];
    const int tid  = threadIdx.x;
    const int wave = tid >> 6, lane = tid & 63;
    const int m0 = blockIdx.y * 128;
    const int n0 = blockIdx.x * 128;
    const bool swap = (MODE == 1) || (blockIdx.x < 16);

    f32x4 acc[4][4] = {};

    const int s0 = tid, s1 = tid + 256;      // slots: row = s>>2, chunk = s&3
    int ar0 = m0 + (s0 >> 2); if (ar0 > NROWS - 1) ar0 = NROWS - 1;
    int ar1 = m0 + (s1 >> 2); if (ar1 > NROWS - 1) ar1 = NROWS - 1;
    const int br0 = n0 + (s0 >> 2);
    const int br1 = n0 + (s1 >> 2);
    const int kc0 = (s0 & 3) * 8, kc1 = (s1 & 3) * 8;

    const ushort_t* ga0 = A + (long)ar0 * DIMC + kc0;
    const ushort_t* ga1 = A + (long)ar1 * DIMC + kc1;
    const ushort_t* gw0 = W + (long)br0 * DIMC + kc0;
    const ushort_t* gw1 = W + (long)br1 * DIMC + kc1;
    ushort_t* la00 = &As0[s0 * 8]; ushort_t* la01 = &As1[s0 * 8];
    ushort_t* la10 = &As0[s1 * 8]; ushort_t* la11 = &As1[s1 * 8];
    ushort_t* lb00 = &Bs0[s0 * 8]; ushort_t* lb01 = &Bs1[s0 * 8];
    ushort_t* lb10 = &Bs0[s1 * 8]; ushort_t* lb11 = &Bs1[s1 * 8];

    const int wm = (wave >> 1) * 64, wn = (wave & 1) * 64;
    const int fr = lane & 15, fk = (lane >> 4) * 8;
    const int arow = (wm + fr) * 32 + fk;    // fragment base offsets
    const int brow = (wn + fr) * 32 + fk;

    for (int k0 = 0; k0 < DIMC; k0 += 64) {
        load_lds16(ga0 + k0,      la00);
        load_lds16(ga0 + k0 + 32, la01);
        load_lds16(ga1 + k0,      la10);
        load_lds16(ga1 + k0 + 32, la11);
        load_lds16(gw0 + k0,      lb00);
        load_lds16(gw0 + k0 + 32, lb01);
        load_lds16(gw1 + k0,      lb10);
        load_lds16(gw1 + k0 + 32, lb11);
        __syncthreads();

        // ---- half 0 (As0/Bs0) ----
        {
            bf16x8 af[4], bfr[4];
            #pragma unroll
            for (int mi = 0; mi < 4; ++mi)
                af[mi] = *(const bf16x8*)&As0[arow + mi * 16 * 32];
            #pragma unroll
            for (int ni = 0; ni < 4; ++ni)
                bfr[ni] = *(const bf16x8*)&Bs0[brow + ni * 16 * 32];
            if (swap) {
                #pragma unroll
                for (int mi = 0; mi < 4; ++mi)
                    #pragma unroll
                    for (int ni = 0; ni < 4; ++ni)
                        acc[mi][ni] = __builtin_amdgcn_mfma_f32_16x16x32_bf16(
                            bfr[ni], af[mi], acc[mi][ni], 0, 0, 0);
            } else {
                #pragma unroll
                for (int mi = 0; mi < 4; ++mi)
                    #pragma unroll
                    for (int ni = 0; ni < 4; ++ni)
                        acc[mi][ni] = __builtin_amdgcn_mfma_f32_16x16x32_bf16(
                            af[mi], bfr[ni], acc[mi][ni], 0, 0, 0);
            }
        }
        // ---- half 1 (As1/Bs1) ----
        {
            bf16x8 af[4], bfr[4];
            #pragma unroll
            for (int mi = 0; mi < 4; ++mi)
                af[mi] = *(const bf16x8*)&As1[arow + mi * 16 * 32];
            #pragma unroll
            for (int ni = 0; ni < 4; ++ni)
                bfr[ni] = *(const bf16x8*)&Bs1[brow + ni * 16 * 32];
            if (swap) {
                #pragma unroll
                for (int mi = 0; mi < 4; ++mi)
                    #pragma unroll
                    for (int ni = 0; ni < 4; ++ni)
                        acc[mi][ni] = __builtin_amdgcn_mfma_f32_16x16x32_bf16(
                            bfr[ni], af[mi], acc[mi][ni], 0, 0, 0);
            } else {
                #pragma unroll
                for (int mi = 0; mi < 4; ++mi)
                    #pragma unroll
                    for (int ni = 0; ni < 4; ++ni)
                        acc[mi][ni] = __builtin_amdgcn_mfma_f32_16x16x32_bf16(
                            af[mi], bfr[ni], acc[mi][ni], 0, 0, 0);
            }
        }
        __syncthreads();
    }

    const int col = lane & 15, rb = (lane >> 4) * 4;

    if (MODE == 0 && swap) {
        // Q/K: D[o][m] -> col=m, regs contiguous in o (=d)
        const int part = n0 >> 10;
        #pragma unroll
        for (int mi = 0; mi < 4; ++mi) {
            const int m = m0 + wm + mi * 16 + col;
            if (m < NROWS) {
                const int bb = m / NTOK, n = m - bb * NTOK;
                #pragma unroll
                for (int ni = 0; ni < 4; ++ni) {
                    const int rem = (n0 & 1023) + wn + ni * 16 + rb;
                    const int hg = rem >> 6, d = rem & 63;
                    ushort4 pk;
                    pk.x = f2bf(acc[mi][ni][0]);
                    pk.y = f2bf(acc[mi][ni][1]);
                    pk.z = f2bf(acc[mi][ni][2]);
                    pk.w = f2bf(acc[mi][ni][3]);
                    *(ushort4*)(QKV + (long)part * QKV_ELEMS +
                        ((long)(bb * 16 + hg) * NTOK + n) * 64 + d) = pk;
                }
            }
        }
    } else if (MODE == 0) {
        // V: D[m][o] -> regs contiguous in m (=n), store to Vt[bh][d][n]
        #pragma unroll
        for (int ni = 0; ni < 4; ++ni) {
            const int o = n0 + wn + ni * 16 + col;
            const int rem = o & 1023;
            const int hg = rem >> 6, d = rem & 63;
            #pragma unroll
            for (int mi = 0; mi < 4; ++mi) {
                const int mb = m0 + wm + mi * 16 + rb;
                if (mb < NROWS) {
                    const int bb = mb / NTOK, n = mb - bb * NTOK;
                    ushort4 pk;
                    pk.x = f2bf(acc[mi][ni][0]);
                    pk.y = f2bf(acc[mi][ni][1]);
                    pk.z = f2bf(acc[mi][ni][2]);
                    pk.w = f2bf(acc[mi][ni][3]);
                    *(ushort4*)(QKV + 2L * QKV_ELEMS +
                        ((long)((bb * 16 + hg) * 64 + d)) * NTOK + n) = pk;
                }
            }
        }
    } else {
        // out proj: col=m, regs contiguous in o -> float4 stores
        #pragma unroll
        for (int mi = 0; mi < 4; ++mi) {
            const int m = m0 + wm + mi * 16 + col;
            if (m < NROWS) {
                #pragma unroll
                for (int ni = 0; ni < 4; ++ni) {
                    const int o = n0 + wn + ni * 16 + rb;
                    float4 pk;
                    pk.x = acc[mi][ni][0];
                    pk.y = acc[mi][ni][1];
                    pk.z = acc[mi][ni][2];
                    pk.w = acc[mi][ni][3];
                    *(float4*)(Out + (long)m * DIMC + o) = pk;
                }
            }
        }
    }
}

// ---------------------------------------------------------------------------
// RMSNorm + RoPE, one THREAD per head-token vector.
// ---------------------------------------------------------------------------
__global__ __launch_bounds__(256) void rope_kernel(
    ushort_t* __restrict__ Qb, ushort_t* __restrict__ Kb,
    const float* __restrict__ cosb, const float* __restrict__ sinb,
    const float* __restrict__ wq, const float* __restrict__ wk)
{
    __shared__ float wsh[64];
    const int idx = blockIdx.x * 256 + threadIdx.x;
    const int tensor = (idx >= 132096) ? 1 : 0;
    const int r = idx - tensor * 132096;
    const int n = r % NTOK;
    if (threadIdx.x < 64) wsh[threadIdx.x] = (tensor ? wk : wq)[threadIdx.x];
    __syncthreads();

    ushort_t* base = (tensor ? Kb : Qb) + (long)r * 64;
    bf16x8 xc[8];
    #pragma unroll
    for (int c = 0; c < 8; ++c) xc[c] = *(const bf16x8*)(base + c * 8);

    float ss = 0.f;
    #pragma unroll
    for (int c = 0; c < 8; ++c) {
        const f32x8 xf = __builtin_convertvector(xc[c], f32x8);
        #pragma unroll
        for (int e = 0; e < 8; ++e) ss += xf[e] * xf[e];
    }
    const float rms = rsqrtf(ss * (1.0f / 64.0f) + 1e-6f);

    const float* cosp = cosb + n * 64;
    const float* sinp = sinb + n * 64;
    #pragma unroll
    for (int c = 0; c < 8; ++c) {
        const f32x8 xf = __builtin_convertvector(xc[c], f32x8);
        const f32x8 pf = __builtin_convertvector(xc[c ^ 4], f32x8);
        const float sgn = (c < 4) ? -1.f : 1.f;
        bf16x8 o8;
        #pragma unroll
        for (int e = 0; e < 8; ++e) {
            const float xn  = xf[e] * rms * wsh[c * 8 + e];
            const float rot = sgn * pf[e] * rms * wsh[(c ^ 4) * 8 + e];
            o8[e] = (__bf16)(xn * cosp[c * 8 + e] + rot * sinp[c * 8 + e]);
        }
        *(bf16x8*)(base + c * 8) = o8;
    }
}

// ---------------------------------------------------------------------------
// Merged attention (specials first, ones-MFMA row sums, V register prefetch,
// XCD-local bh mapping). Unchanged from round 12.
// ---------------------------------------------------------------------------
__global__ __launch_bounds__(256) void attn_kernel(
    const ushort_t* __restrict__ Qb, const ushort_t* __restrict__ Kb,
    const ushort_t* __restrict__ Vt, ushort_t* __restrict__ AO)
{
    __shared__ __align__(16) ushort_t KP_s[256 * 72];

    const int tid = threadIdx.x;
    const int wave = tid >> 6, lane = tid & 63;
    const int m_ = lane & 15, quad = lane >> 4;
    const int nb = wave * 64;
    const int d0 = wave * 16;

    bf16x8 ones;
    #pragma unroll
    for (int e = 0; e < 8; ++e) ones[e] = (__bf16)1.0f;

    if (blockIdx.x >= 128) {
        // ================= PATCH =================
        const int blk = blockIdx.x - 128;
        const int bh = blk & 127, qr = blk >> 7;
        const int b = bh >> 4, h = bh & 15;

        int r0 = qr - 3; if (r0 < 0) r0 = 0;
        int r1 = qr + 3; if (r1 > 31) r1 = 31;
        const int limit = 8 + (r1 - r0 + 1) * 32;

        const ushort_t* Qg  = Qb + ((long)bh * NTOK + 8 + qr * 32) * 64;
        const ushort_t* Kg  = Kb + (long)bh * NTOK * 64;
        const ushort_t* Vtg = Vt + (long)bh * 64 * NTOK;

        bf16x8 af[2][2];
        #pragma unroll
        for (int mt = 0; mt < 2; ++mt)
            #pragma unroll
            for (int ks = 0; ks < 2; ++ks)
                af[mt][ks] = *(const bf16x8*)(Qg + (mt * 16 + m_) * 64 + ks * 32 + quad * 8);

        bf16x8 bv[8];
        #pragma unroll
        for (int ks = 0; ks < 8; ++ks) {
            const int slot0 = ks * 32 + quad * 8;
            int tok0;
            if (slot0 >= limit) tok0 = 0;
            else if (slot0 < 8) tok0 = slot0;
            else tok0 = 8 + r0 * 32 + (slot0 - 8);
            bv[ks] = *(const bf16x8*)(Vtg + (long)(d0 + m_) * NTOK + tok0);
        }

        for (int c = tid; c < limit * 8; c += 256) {
            const int slot = c >> 3, c8 = (c & 7) * 8;
            const int tok = slot + (slot >= 8 ? r0 * 32 : 0);
            *(bf16x8*)&KP_s[slot * 72 + c8] = *(const bf16x8*)(Kg + (long)tok * 64 + c8);
        }
        __syncthreads();

        bf16x8 bfr[4][2];
        #pragma unroll
        for (int nt = 0; nt < 4; ++nt)
            #pragma unroll
            for (int ks = 0; ks < 2; ++ks)
                bfr[nt][ks] = *(const bf16x8*)&KP_s[(nb + nt * 16 + m_) * 72 + ks * 32 + quad * 8];

        f32x4 sacc[2][4] = {};
        #pragma unroll
        for (int mt = 0; mt < 2; ++mt)
            #pragma unroll
            for (int nt = 0; nt < 4; ++nt) {
                sacc[mt][nt] = __builtin_amdgcn_mfma_f32_16x16x32_bf16(
                    af[mt][0], bfr[nt][0], sacc[mt][nt], 0, 0, 0);
                sacc[mt][nt] = __builtin_amdgcn_mfma_f32_16x16x32_bf16(
                    af[mt][1], bfr[nt][1], sacc[mt][nt], 0, 0, 0);
            }
        __syncthreads();

        #pragma unroll
        for (int mt = 0; mt < 2; ++mt)
            #pragma unroll
            for (int nt = 0; nt < 4; ++nt) {
                const int slot = nb + nt * 16 + m_;
                const int kc = (slot - 8) & 31;
                #pragma unroll
                for (int reg = 0; reg < 4; ++reg) {
                    const int qm = mt * 16 + quad * 4 + reg;
                    const bool val = (slot < 8) ||
                        ((slot < limit) && ((unsigned)(kc - qm + 3) <= 6u));
                    const float p = val ? __expf(sacc[mt][nt][reg] * 0.125f) : 0.f;
                    KP_s[qm * 280 + slot] = f2bf(p);
                }
            }
        __syncthreads();

        f32x4 oacc[2] = {}, lacc[2] = {};
        #pragma unroll
        for (int ks = 0; ks < 8; ++ks) {
            #pragma unroll
            for (int mt = 0; mt < 2; ++mt) {
                const bf16x8 ap = *(const bf16x8*)&KP_s[(mt * 16 + m_) * 280 + ks * 32 + quad * 8];
                oacc[mt] = __builtin_amdgcn_mfma_f32_16x16x32_bf16(ap, bv[ks], oacc[mt], 0, 0, 0);
                lacc[mt] = __builtin_amdgcn_mfma_f32_16x16x32_bf16(ap, ones,   lacc[mt], 0, 0, 0);
            }
        }
        #pragma unroll
        for (int mt = 0; mt < 2; ++mt)
            #pragma unroll
            for (int reg = 0; reg < 4; ++reg) {
                const int qm = mt * 16 + quad * 4 + reg;
                const int tok = 8 + qr * 32 + qm;
                AO[((long)(b * NTOK + tok)) * DIMC + h * 64 + d0 + m_] =
                    f2bf(oacc[mt][reg] / lacc[mt][reg]);
            }
    } else {
        // ================= SPECIAL =================
        const int bh = blockIdx.x;
        const int b = bh >> 4, h = bh & 15;
        const ushort_t* Kg  = Kb + (long)bh * NTOK * 64;
        const ushort_t* Vtg = Vt + (long)bh * 64 * NTOK;

        bf16x8 afs[2];
        if (m_ < 8) {
            #pragma unroll
            for (int ks = 0; ks < 2; ++ks)
                afs[ks] = *(const bf16x8*)(Qb + ((long)bh * NTOK + m_) * 64 + ks * 32 + quad * 8);
        } else {
            #pragma unroll
            for (int ks = 0; ks < 2; ++ks)
                #pragma unroll
                for (int e = 0; e < 8; ++e) afs[ks][e] = (__bf16)0.f;
        }

        f32x4 oacc = {}, lacc = {};
        for (int ch = 0; ch < 5; ++ch) {
            const int tok0 = ch * 256;
            const int limit = (NTOK - tok0 < 256) ? (NTOK - tok0) : 256;

            bf16x8 bv[8];
            #pragma unroll
            for (int ks = 0; ks < 8; ++ks) {
                const int slot0 = ks * 32 + quad * 8;
                const int tok = tok0 + ((slot0 < limit) ? slot0 : 0);
                bv[ks] = *(const bf16x8*)(Vtg + (long)(d0 + m_) * NTOK + tok);
            }

            __syncthreads();
            for (int c = tid; c < limit * 8; c += 256) {
                const int slot = c >> 3, c8 = (c & 7) * 8;
                *(bf16x8*)&KP_s[slot * 72 + c8] =
                    *(const bf16x8*)(Kg + (long)(tok0 + slot) * 64 + c8);
            }
            __syncthreads();

            bf16x8 bfr[4][2];
            #pragma unroll
            for (int nt = 0; nt < 4; ++nt)
                #pragma unroll
                for (int ks = 0; ks < 2; ++ks)
                    bfr[nt][ks] = *(const bf16x8*)&KP_s[(nb + nt * 16 + m_) * 72 + ks * 32 + quad * 8];
            f32x4 sacc[4] = {};
            #pragma unroll
            for (int nt = 0; nt < 4; ++nt) {
                sacc[nt] = __builtin_amdgcn_mfma_f32_16x16x32_bf16(afs[0], bfr[nt][0], sacc[nt], 0, 0, 0);
                sacc[nt] = __builtin_amdgcn_mfma_f32_16x16x32_bf16(afs[1], bfr[nt][1], sacc[nt], 0, 0, 0);
            }
            __syncthreads();

            #pragma unroll
            for (int nt = 0; nt < 4; ++nt) {
                const int slot = nb + nt * 16 + m_;
                const bool val = (slot < limit);
                #pragma unroll
                for (int reg = 0; reg < 4; ++reg) {
                    const int qm = quad * 4 + reg;
                    const float p = val ? __expf(sacc[nt][reg] * 0.125f) : 0.f;
                    KP_s[qm * 280 + slot] = f2bf(p);
                }
            }
            __syncthreads();

            #pragma unroll
            for (int ks = 0; ks < 8; ++ks) {
                const bf16x8 ap = *(const bf16x8*)&KP_s[m_ * 280 + ks * 32 + quad * 8];
                oacc = __builtin_amdgcn_mfma_f32_16x16x32_bf16(ap, bv[ks], oacc, 0, 0, 0);
                lacc = __builtin_amdgcn_mfma_f32_16x16x32_bf16(ap, ones,   lacc, 0, 0, 0);
            }
        }

        #pragma unroll
        for (int reg = 0; reg < 4; ++reg) {
            const int qm = quad * 4 + reg;
            if (qm < 8) {
                AO[((long)(b * NTOK + qm)) * DIMC + h * 64 + d0 + m_] =
                    f2bf(oacc[reg] / lacc[reg]);
            }
        }
    }
}

extern "C" void kernel_launch(void* const* d_in, const int* in_sizes, int n_in,
                              void* d_out, int out_size, void* d_ws, size_t ws_size,
                              hipStream_t stream) {
    const float* X    = (const float*)d_in[0];
    const float* fc   = (const float*)d_in[1];
    const float* fs   = (const float*)d_in[2];
    const float* qkvw = (const float*)d_in[3];
    const float* outw = (const float*)d_in[4];
    const float* nqw  = (const float*)d_in[5];
    const float* nkw  = (const float*)d_in[6];

    ushort_t* Qb  = (ushort_t*)d_ws;     // 16.9 MB each
    ushort_t* Kb  = Qb + QKV_ELEMS;
    ushort_t* Vt  = Kb + QKV_ELEMS;      // dim-major [bh][d][n]
    ushort_t* AO  = Vt + QKV_ELEMS;
    ushort_t* Xb  = AO + QKV_ELEMS;      // bf16 X (16.9 MB)
    ushort_t* Wqb = Xb + XE;             // bf16 qkv_w (6.3 MB)
    ushort_t* Wob = Wqb + QWE;           // bf16 out_w (2.1 MB)
    float* Out = (float*)d_out;

    cvt_kernel<<<6176, 256, 0, stream>>>(X, qkvw, outw, Xb, Wqb, Wob);
    gemm_kernel<0><<<dim3(24, 65), 256, 0, stream>>>(Xb, Wqb, Qb, nullptr);
    rope_kernel<<<1032, 256, 0, stream>>>(Qb, Kb, fc, fs, nqw, nkw);
    attn_kernel<<<4224, 256, 0, stream>>>(Qb, Kb, Vt, AO);
    gemm_kernel<1><<<dim3(8, 65), 256, 0, stream>>>(AO, Wob, nullptr, Out);
}